// Round 3
// baseline (396.009 us; speedup 1.0000x reference)
//
#include <hip/hip_runtime.h>

static constexpr int N_NODES = 50000;
static constexpr int N_EDGES = 800000;
static constexpr float NEG_BIG = -3.0e38f;

__device__ __forceinline__ float bf2f(unsigned short u) {
  union { unsigned int i; float f; } v; v.i = ((unsigned int)u) << 16; return v.f;
}
__device__ __forceinline__ unsigned short f2bf(float f) {
  union { unsigned int i; float f; } v; v.f = f;
  unsigned int r = (v.i + 0x7fffu + ((v.i >> 16) & 1u)) >> 16;
  return (unsigned short)r;
}
__device__ __forceinline__ int clampN(int v) {
  unsigned u = (unsigned)v; return (u < (unsigned)N_NODES) ? (int)u : 0;
}

// If edge buffer is raw int64 (little-endian, values < 2^31), odd int32 words are all 0.
__global__ void k_detect(const int* __restrict__ ei, int* __restrict__ flag) {
  if (threadIdx.x == 0 && blockIdx.x == 0) {
    int z = ei[1] | ei[3] | ei[5] | ei[7];
    *flag = (z == 0) ? 1 : 0;
  }
}

__global__ void k_zero_out(float* __restrict__ out, int n) {
  int i = blockIdx.x * 256 + threadIdx.x;
  if (i < n) out[i] = 0.f;
}

// c_dst[k] = sum_c w_dst[k][c] * a_dst[c]  (alpha_d = x . c_dst; kills the hd GEMMs)
__global__ void k_precompute(const float* __restrict__ w1_dst, const float* __restrict__ a1_dst,
                             const float* __restrict__ w2_dst, const float* __restrict__ a2_dst,
                             float* __restrict__ c1dst, float* __restrict__ c2dst) {
  int k = threadIdx.x;
  if (k < 128) {
    float s1 = 0.f;
    for (int c = 0; c < 128; ++c) s1 += w1_dst[k * 128 + c] * a1_dst[c];
    c1dst[k] = s1;
    float s2 = 0.f;
    for (int c = 0; c < 64; ++c) s2 += w2_dst[k * 64 + c] * a2_dst[c];
    c2dst[k] = s2;
  }
}

// hs1 = x @ w1_src (bf16 out) ; linzb = x @ lin1_w + lin1_b (bf16 out)
__global__ __launch_bounds__(256) void k_gemm1(
    const float* __restrict__ x, const float* __restrict__ wsrc,
    const float* __restrict__ wlin, const float* __restrict__ lin_b,
    unsigned short* __restrict__ hs1, unsigned short* __restrict__ linzb) {
  __shared__ float xs[16][128];
  int nb = blockIdx.x * 16;
  const float4* x4 = (const float4*)x;  // row = 32 float4
  for (int t = threadIdx.x; t < 512; t += 256) {
    int nn = t >> 5, q = t & 31;
    float4 v = x4[(size_t)(nb + nn) * 32 + q];
    *(float4*)&xs[nn][q * 4] = v;
  }
  __syncthreads();
  int c = threadIdx.x;
  const float* w;
  int cc;
  if (c < 128) { w = wsrc; cc = c; } else { w = wlin; cc = c - 128; }
  float acc[16];
#pragma unroll
  for (int i = 0; i < 16; ++i) acc[i] = 0.f;
  for (int k = 0; k < 128; ++k) {
    float wv = w[k * 128 + cc];
#pragma unroll
    for (int i = 0; i < 16; ++i) acc[i] += xs[i][k] * wv;
  }
  if (c < 128) {
#pragma unroll
    for (int i = 0; i < 16; ++i) hs1[(size_t)(nb + i) * 128 + cc] = f2bf(acc[i]);
  } else {
    float bb = lin_b[cc];
#pragma unroll
    for (int i = 0; i < 16; ++i) linzb[(size_t)(nb + i) * 128 + cc] = f2bf(acc[i] + bb);
  }
}

// hs2 = zb @ w2_src  (zb bf16 in, bf16 out)
__global__ __launch_bounds__(256) void k_gemm2(
    const unsigned short* __restrict__ zb, const float* __restrict__ w2,
    unsigned short* __restrict__ hs2) {
  __shared__ float zs[16][128];
  int nb = blockIdx.x * 16;
  const unsigned int* zu = (const unsigned int*)zb;  // row = 64 uints
  for (int t = threadIdx.x; t < 1024; t += 256) {
    int nn = t >> 6, kk = t & 63;
    unsigned int v = zu[(size_t)(nb + nn) * 64 + kk];
    zs[nn][kk * 2]     = bf2f((unsigned short)(v & 0xffffu));
    zs[nn][kk * 2 + 1] = bf2f((unsigned short)(v >> 16));
  }
  __syncthreads();
  int c = threadIdx.x & 63;
  int g = threadIdx.x >> 6;
  float acc[4] = {0.f, 0.f, 0.f, 0.f};
  for (int k = 0; k < 128; ++k) {
    float wv = w2[k * 64 + c];
#pragma unroll
    for (int i = 0; i < 4; ++i) acc[i] += zs[g * 4 + i][k] * wv;
  }
#pragma unroll
  for (int i = 0; i < 4; ++i) hs2[(size_t)(nb + g * 4 + i) * 64 + c] = f2bf(acc[i]);
}

// as[n] = hs[n].asrc ; ad[n] = xin[n].cdst   (one wave per node)
template <int C, bool XBF>
__global__ __launch_bounds__(256) void k_alpha(
    const unsigned short* __restrict__ hs, const float* __restrict__ asrc,
    const void* __restrict__ xin, const float* __restrict__ cdst,
    float* __restrict__ as_, float* __restrict__ ad_) {
  int node = (int)((blockIdx.x * 256 + threadIdx.x) >> 6);
  if (node >= N_NODES) return;
  int lane = threadIdx.x & 63;
  float sa = 0.f;
#pragma unroll
  for (int k = lane; k < C; k += 64) sa += bf2f(hs[(size_t)node * C + k]) * asrc[k];
  float sd = 0.f;
  if (XBF) {
    const unsigned short* xb = (const unsigned short*)xin;
#pragma unroll
    for (int k = lane; k < 128; k += 64) sd += bf2f(xb[(size_t)node * 128 + k]) * cdst[k];
  } else {
    const float* xf = (const float*)xin;
#pragma unroll
    for (int k = lane; k < 128; k += 64) sd += xf[(size_t)node * 128 + k] * cdst[k];
  }
#pragma unroll
  for (int o = 32; o > 0; o >>= 1) {
    sa += __shfl_xor(sa, o, 64);
    sd += __shfl_xor(sd, o, 64);
  }
  if (lane == 0) { as_[node] = sa; ad_[node] = sd; }
}

__global__ void k_count(const int* __restrict__ ei, const int* __restrict__ flag,
                        int* __restrict__ deg) {
  int e = blockIdx.x * 256 + threadIdx.x;
  if (e < N_EDGES) {
    int f = *flag;
    int d = clampN(ei[(size_t)(N_EDGES + e) << f]);
    atomicAdd(&deg[d], 1);
  }
}

__global__ __launch_bounds__(256) void k_scan1(const int* __restrict__ deg,
                                               int* __restrict__ offs,
                                               int* __restrict__ bsums, int n) {
  __shared__ int wsum[4];
  int i = blockIdx.x * 256 + threadIdx.x;
  int lane = threadIdx.x & 63, wid = threadIdx.x >> 6;
  int v = (i < n) ? deg[i] : 0;
  int s = v;
#pragma unroll
  for (int o = 1; o < 64; o <<= 1) { int t = __shfl_up(s, o, 64); if (lane >= o) s += t; }
  if (lane == 63) wsum[wid] = s;
  __syncthreads();
  if (threadIdx.x == 0) {
    int a = 0;
#pragma unroll
    for (int w = 0; w < 4; ++w) { a += wsum[w]; wsum[w] = a; }
  }
  __syncthreads();
  int base = (wid > 0) ? wsum[wid - 1] : 0;
  if (i < n) offs[i] = base + s - v;
  if (threadIdx.x == 0) bsums[blockIdx.x] = wsum[3];
}

__global__ __launch_bounds__(256) void k_scan2(int* __restrict__ bsums, int nb,
                                               int* __restrict__ offs, int n, int etot) {
  __shared__ int wsum[4];
  int tid = threadIdx.x, lane = tid & 63, wid = tid >> 6;
  int v = (tid < nb) ? bsums[tid] : 0;
  int s = v;
#pragma unroll
  for (int o = 1; o < 64; o <<= 1) { int t = __shfl_up(s, o, 64); if (lane >= o) s += t; }
  if (lane == 63) wsum[wid] = s;
  __syncthreads();
  if (tid == 0) {
    int a = 0;
#pragma unroll
    for (int w = 0; w < 4; ++w) { a += wsum[w]; wsum[w] = a; }
  }
  __syncthreads();
  int base = (wid > 0) ? wsum[wid - 1] : 0;
  if (tid < nb) bsums[tid] = base + s - v;
  if (tid == 0) offs[n] = etot;
}

__global__ __launch_bounds__(256) void k_scan3(int* __restrict__ offs, int* __restrict__ cursor,
                                               const int* __restrict__ bsums, int n) {
  int i = blockIdx.x * 256 + threadIdx.x;
  if (i < n) {
    int o = offs[i] + bsums[blockIdx.x];
    offs[i] = o;
    cursor[i] = o;
  }
}

__global__ void k_fill(const int* __restrict__ ei, const int* __restrict__ flag,
                       int* __restrict__ cursor, int* __restrict__ ssrc) {
  int e = blockIdx.x * 256 + threadIdx.x;
  if (e < N_EDGES) {
    int f = *flag;
    int s = clampN(ei[(size_t)e << f]);
    int d = clampN(ei[(size_t)(N_EDGES + e) << f]);
    int p = atomicAdd(&cursor[d], 1);
    if ((unsigned)p < (unsigned)N_EDGES) ssrc[p] = s;
  }
}

// layer-1 aggregation + fused relu(agg + b1 + lin); reads linzb[node], writes zb over it
__global__ __launch_bounds__(256) void k_agg1(
    const int* __restrict__ offs, const int* __restrict__ ssrc,
    const float* __restrict__ as1, const float* __restrict__ ad1,
    const unsigned short* __restrict__ hs1, const float* __restrict__ b1,
    unsigned short* __restrict__ linzb) {
  int node = (int)((blockIdx.x * 256 + threadIdx.x) >> 6);
  if (node >= N_NODES) return;
  int lane = threadIdx.x & 63;
  int o0 = offs[node], o1 = offs[node + 1];
  if (!((unsigned)o0 <= (unsigned)N_EDGES && (unsigned)o1 <= (unsigned)N_EDGES && o0 <= o1))
    { o0 = 0; o1 = 0; }
  int deg = o1 - o0;
  float ad = ad1[node];
  float m = NEG_BIG;
  for (int j = lane; j < deg; j += 64) {
    int s = clampN(ssrc[o0 + j]);
    float e = as1[s] + ad;
    e = e > 0.f ? e : 0.2f * e;
    m = fmaxf(m, e);
  }
#pragma unroll
  for (int o = 32; o > 0; o >>= 1) m = fmaxf(m, __shfl_xor(m, o, 64));
  float ssum = 0.f;
  for (int j = lane; j < deg; j += 64) {
    int s = clampN(ssrc[o0 + j]);
    float e = as1[s] + ad;
    e = e > 0.f ? e : 0.2f * e;
    ssum += __expf(e - m);
  }
#pragma unroll
  for (int o = 32; o > 0; o >>= 1) ssum += __shfl_xor(ssum, o, 64);
  float inv = 1.f / (ssum + 1e-16f);
  float acc0 = 0.f, acc1 = 0.f;
  for (int j = 0; j < deg; ++j) {
    int s = clampN(ssrc[o0 + j]);
    float e = as1[s] + ad;
    e = e > 0.f ? e : 0.2f * e;
    float wj = __expf(e - m) * inv;
    unsigned int hv = *(const unsigned int*)(hs1 + (size_t)s * 128 + lane * 2);
    acc0 += wj * bf2f((unsigned short)(hv & 0xffffu));
    acc1 += wj * bf2f((unsigned short)(hv >> 16));
  }
  int c = lane * 2;
  unsigned int lv = *(const unsigned int*)(linzb + (size_t)node * 128 + c);
  float z0 = acc0 + b1[c] + bf2f((unsigned short)(lv & 0xffffu));
  float z1 = acc1 + b1[c + 1] + bf2f((unsigned short)(lv >> 16));
  z0 = z0 > 0.f ? z0 : 0.f;
  z1 = z1 > 0.f ? z1 : 0.f;
  unsigned int ov = (unsigned int)f2bf(z0) | ((unsigned int)f2bf(z1) << 16);
  *(unsigned int*)(linzb + (size_t)node * 128 + c) = ov;
}

// layer-2 aggregation, fp32 final output (+b2)
__global__ __launch_bounds__(256) void k_agg2(
    const int* __restrict__ offs, const int* __restrict__ ssrc,
    const float* __restrict__ as2, const float* __restrict__ ad2,
    const unsigned short* __restrict__ hs2, const float* __restrict__ b2,
    float* __restrict__ out) {
  int node = (int)((blockIdx.x * 256 + threadIdx.x) >> 6);
  if (node >= N_NODES) return;
  int lane = threadIdx.x & 63;
  int o0 = offs[node], o1 = offs[node + 1];
  if (!((unsigned)o0 <= (unsigned)N_EDGES && (unsigned)o1 <= (unsigned)N_EDGES && o0 <= o1))
    { o0 = 0; o1 = 0; }
  int deg = o1 - o0;
  float ad = ad2[node];
  float m = NEG_BIG;
  for (int j = lane; j < deg; j += 64) {
    int s = clampN(ssrc[o0 + j]);
    float e = as2[s] + ad;
    e = e > 0.f ? e : 0.2f * e;
    m = fmaxf(m, e);
  }
#pragma unroll
  for (int o = 32; o > 0; o >>= 1) m = fmaxf(m, __shfl_xor(m, o, 64));
  float ssum = 0.f;
  for (int j = lane; j < deg; j += 64) {
    int s = clampN(ssrc[o0 + j]);
    float e = as2[s] + ad;
    e = e > 0.f ? e : 0.2f * e;
    ssum += __expf(e - m);
  }
#pragma unroll
  for (int o = 32; o > 0; o >>= 1) ssum += __shfl_xor(ssum, o, 64);
  float inv = 1.f / (ssum + 1e-16f);
  float acc = 0.f;
  for (int j = 0; j < deg; ++j) {
    int s = clampN(ssrc[o0 + j]);
    float e = as2[s] + ad;
    e = e > 0.f ? e : 0.2f * e;
    float wj = __expf(e - m) * inv;
    acc += wj * bf2f(hs2[(size_t)s * 64 + lane]);
  }
  out[(size_t)node * 64 + lane] = acc + b2[lane];
}

extern "C" void kernel_launch(void* const* d_in, const int* in_sizes, int n_in,
                              void* d_out, int out_size, void* d_ws, size_t ws_size,
                              hipStream_t stream) {
  (void)in_sizes; (void)n_in;
  const float* x      = (const float*)d_in[0];
  const int*   ei     = (const int*)d_in[1];
  const float* lin1_w = (const float*)d_in[2];
  const float* lin1_b = (const float*)d_in[3];
  const float* w1_src = (const float*)d_in[4];
  const float* w1_dst = (const float*)d_in[5];
  const float* a1_src = (const float*)d_in[6];
  const float* a1_dst = (const float*)d_in[7];
  const float* b1     = (const float*)d_in[8];
  const float* w2_src = (const float*)d_in[9];
  const float* w2_dst = (const float*)d_in[10];
  const float* a2_src = (const float*)d_in[11];
  const float* a2_dst = (const float*)d_in[12];
  const float* b2     = (const float*)d_in[13];
  float* out = (float*)d_out;

  char* ws = (char*)d_ws;
  size_t off = 0;
  auto alloc = [&](size_t bytes) -> void* {
    void* p = ws + off;
    off += (bytes + 255) & ~(size_t)255;
    return p;
  };
  int* flag    = (int*)alloc(256);
  float* c1dst = (float*)alloc(128 * 4);
  float* c2dst = (float*)alloc(128 * 4);
  int* deg     = (int*)alloc((size_t)N_NODES * 4);
  int* offs    = (int*)alloc((size_t)(N_NODES + 1) * 4);
  int* cursor  = (int*)alloc((size_t)N_NODES * 4);
  int* bsums   = (int*)alloc(1024);
  float* as1   = (float*)alloc((size_t)N_NODES * 4);
  float* ad1   = (float*)alloc((size_t)N_NODES * 4);
  float* as2   = (float*)alloc((size_t)N_NODES * 4);
  float* ad2   = (float*)alloc((size_t)N_NODES * 4);
  int* ssrc    = (int*)alloc((size_t)N_EDGES * 4);
  unsigned short* hs1   = (unsigned short*)alloc((size_t)N_NODES * 128 * 2);
  unsigned short* hs2   = (unsigned short*)alloc((size_t)N_NODES * 64 * 2);
  unsigned short* linzb = (unsigned short*)alloc((size_t)N_NODES * 128 * 2);

  if (off > ws_size) {
    k_zero_out<<<(out_size + 255) / 256, 256, 0, stream>>>(out, out_size);
    return;
  }

  hipMemsetAsync(deg, 0, (size_t)N_NODES * 4, stream);
  k_detect<<<1, 64, 0, stream>>>(ei, flag);
  k_precompute<<<1, 128, 0, stream>>>(w1_dst, a1_dst, w2_dst, a2_dst, c1dst, c2dst);
  k_gemm1<<<N_NODES / 16, 256, 0, stream>>>(x, w1_src, lin1_w, lin1_b, hs1, linzb);
  k_count<<<(N_EDGES + 255) / 256, 256, 0, stream>>>(ei, flag, deg);
  int nb = (N_NODES + 255) / 256;  // 196
  k_scan1<<<nb, 256, 0, stream>>>(deg, offs, bsums, N_NODES);
  k_scan2<<<1, 256, 0, stream>>>(bsums, nb, offs, N_NODES, N_EDGES);
  k_scan3<<<nb, 256, 0, stream>>>(offs, cursor, bsums, N_NODES);
  k_fill<<<(N_EDGES + 255) / 256, 256, 0, stream>>>(ei, flag, cursor, ssrc);
  k_alpha<128, false><<<(N_NODES + 3) / 4, 256, 0, stream>>>(hs1, a1_src, x, c1dst, as1, ad1);
  k_agg1<<<(N_NODES + 3) / 4, 256, 0, stream>>>(offs, ssrc, as1, ad1, hs1, b1, linzb);
  k_gemm2<<<N_NODES / 16, 256, 0, stream>>>(linzb, w2_src, hs2);
  k_alpha<64, true><<<(N_NODES + 3) / 4, 256, 0, stream>>>(hs2, a2_src, linzb, c2dst, as2, ad2);
  k_agg2<<<(N_NODES + 3) / 4, 256, 0, stream>>>(offs, ssrc, as2, ad2, hs2, b2, out);
}

// Round 4
// 296.937 us; speedup vs baseline: 1.3336x; 1.3336x over previous
//
#include <hip/hip_runtime.h>

static constexpr int N_NODES = 50000;
static constexpr int N_EDGES = 800000;
static constexpr float NEG_BIG = -3.0e38f;

__device__ __forceinline__ float bf2f(unsigned short u) {
  union { unsigned int i; float f; } v; v.i = ((unsigned int)u) << 16; return v.f;
}
__device__ __forceinline__ unsigned short f2bf(float f) {
  union { unsigned int i; float f; } v; v.f = f;
  unsigned int r = (v.i + 0x7fffu + ((v.i >> 16) & 1u)) >> 16;
  return (unsigned short)r;
}
__device__ __forceinline__ int clampN(int v) {
  unsigned u = (unsigned)v; return (u < (unsigned)N_NODES) ? (int)u : 0;
}

// If edge buffer is raw int64 (little-endian, values < 2^31), odd int32 words are all 0.
__global__ void k_detect(const int* __restrict__ ei, int* __restrict__ flag) {
  if (threadIdx.x == 0 && blockIdx.x == 0) {
    int z = ei[1] | ei[3] | ei[5] | ei[7];
    *flag = (z == 0) ? 1 : 0;
  }
}

__global__ void k_zero_out(float* __restrict__ out, int n) {
  int i = blockIdx.x * 256 + threadIdx.x;
  if (i < n) out[i] = 0.f;
}

// c_dst[k] = sum_c w_dst[k][c] * a_dst[c]
__global__ void k_precompute(const float* __restrict__ w1_dst, const float* __restrict__ a1_dst,
                             const float* __restrict__ w2_dst, const float* __restrict__ a2_dst,
                             float* __restrict__ c1dst, float* __restrict__ c2dst) {
  int k = threadIdx.x;
  if (k < 128) {
    float s1 = 0.f;
    for (int c = 0; c < 128; ++c) s1 += w1_dst[k * 128 + c] * a1_dst[c];
    c1dst[k] = s1;
    float s2 = 0.f;
    for (int c = 0; c < 64; ++c) s2 += w2_dst[k * 64 + c] * a2_dst[c];
    c2dst[k] = s2;
  }
}

// hs1 = x @ w1_src (bf16 out) ; linzb = x @ lin1_w + lin1_b (bf16 out)
__global__ __launch_bounds__(256) void k_gemm1(
    const float* __restrict__ x, const float* __restrict__ wsrc,
    const float* __restrict__ wlin, const float* __restrict__ lin_b,
    unsigned short* __restrict__ hs1, unsigned short* __restrict__ linzb) {
  __shared__ float xs[16][128];
  int nb = blockIdx.x * 16;
  const float4* x4 = (const float4*)x;
  for (int t = threadIdx.x; t < 512; t += 256) {
    int nn = t >> 5, q = t & 31;
    float4 v = x4[(size_t)(nb + nn) * 32 + q];
    *(float4*)&xs[nn][q * 4] = v;
  }
  __syncthreads();
  int c = threadIdx.x;
  const float* w;
  int cc;
  if (c < 128) { w = wsrc; cc = c; } else { w = wlin; cc = c - 128; }
  float acc[16];
#pragma unroll
  for (int i = 0; i < 16; ++i) acc[i] = 0.f;
  for (int k = 0; k < 128; ++k) {
    float wv = w[k * 128 + cc];
#pragma unroll
    for (int i = 0; i < 16; ++i) acc[i] += xs[i][k] * wv;
  }
  if (c < 128) {
#pragma unroll
    for (int i = 0; i < 16; ++i) hs1[(size_t)(nb + i) * 128 + cc] = f2bf(acc[i]);
  } else {
    float bb = lin_b[cc];
#pragma unroll
    for (int i = 0; i < 16; ++i) linzb[(size_t)(nb + i) * 128 + cc] = f2bf(acc[i] + bb);
  }
}

// hs2 = zb @ w2_src
__global__ __launch_bounds__(256) void k_gemm2(
    const unsigned short* __restrict__ zb, const float* __restrict__ w2,
    unsigned short* __restrict__ hs2) {
  __shared__ float zs[16][128];
  int nb = blockIdx.x * 16;
  const unsigned int* zu = (const unsigned int*)zb;
  for (int t = threadIdx.x; t < 1024; t += 256) {
    int nn = t >> 6, kk = t & 63;
    unsigned int v = zu[(size_t)(nb + nn) * 64 + kk];
    zs[nn][kk * 2]     = bf2f((unsigned short)(v & 0xffffu));
    zs[nn][kk * 2 + 1] = bf2f((unsigned short)(v >> 16));
  }
  __syncthreads();
  int c = threadIdx.x & 63;
  int g = threadIdx.x >> 6;
  float acc[4] = {0.f, 0.f, 0.f, 0.f};
  for (int k = 0; k < 128; ++k) {
    float wv = w2[k * 64 + c];
#pragma unroll
    for (int i = 0; i < 4; ++i) acc[i] += zs[g * 4 + i][k] * wv;
  }
#pragma unroll
  for (int i = 0; i < 4; ++i) hs2[(size_t)(nb + g * 4 + i) * 64 + c] = f2bf(acc[i]);
}

// as[n] = hs[n].asrc ; ad[n] = xin[n].cdst   (one wave per node)
template <int C, bool XBF>
__global__ __launch_bounds__(256) void k_alpha(
    const unsigned short* __restrict__ hs, const float* __restrict__ asrc,
    const void* __restrict__ xin, const float* __restrict__ cdst,
    float* __restrict__ as_, float* __restrict__ ad_) {
  int node = (int)((blockIdx.x * 256 + threadIdx.x) >> 6);
  if (node >= N_NODES) return;
  int lane = threadIdx.x & 63;
  float sa = 0.f;
#pragma unroll
  for (int k = lane; k < C; k += 64) sa += bf2f(hs[(size_t)node * C + k]) * asrc[k];
  float sd = 0.f;
  if (XBF) {
    const unsigned short* xb = (const unsigned short*)xin;
#pragma unroll
    for (int k = lane; k < 128; k += 64) sd += bf2f(xb[(size_t)node * 128 + k]) * cdst[k];
  } else {
    const float* xf = (const float*)xin;
#pragma unroll
    for (int k = lane; k < 128; k += 64) sd += xf[(size_t)node * 128 + k] * cdst[k];
  }
#pragma unroll
  for (int o = 32; o > 0; o >>= 1) {
    sa += __shfl_xor(sa, o, 64);
    sd += __shfl_xor(sd, o, 64);
  }
  if (lane == 0) { as_[node] = sa; ad_[node] = sd; }
}

__global__ void k_count(const int* __restrict__ ei, const int* __restrict__ flag,
                        int* __restrict__ deg) {
  int e = blockIdx.x * 256 + threadIdx.x;
  if (e < N_EDGES) {
    int f = *flag;
    int d = clampN(ei[(size_t)(N_EDGES + e) << f]);
    atomicAdd(&deg[d], 1);
  }
}

__global__ __launch_bounds__(256) void k_scan1(const int* __restrict__ deg,
                                               int* __restrict__ offs,
                                               int* __restrict__ bsums, int n) {
  __shared__ int wsum[4];
  int i = blockIdx.x * 256 + threadIdx.x;
  int lane = threadIdx.x & 63, wid = threadIdx.x >> 6;
  int v = (i < n) ? deg[i] : 0;
  int s = v;
#pragma unroll
  for (int o = 1; o < 64; o <<= 1) { int t = __shfl_up(s, o, 64); if (lane >= o) s += t; }
  if (lane == 63) wsum[wid] = s;
  __syncthreads();
  if (threadIdx.x == 0) {
    int a = 0;
#pragma unroll
    for (int w = 0; w < 4; ++w) { a += wsum[w]; wsum[w] = a; }
  }
  __syncthreads();
  int base = (wid > 0) ? wsum[wid - 1] : 0;
  if (i < n) offs[i] = base + s - v;
  if (threadIdx.x == 0) bsums[blockIdx.x] = wsum[3];
}

__global__ __launch_bounds__(256) void k_scan2(int* __restrict__ bsums, int nb,
                                               int* __restrict__ offs, int n, int etot) {
  __shared__ int wsum[4];
  int tid = threadIdx.x, lane = tid & 63, wid = tid >> 6;
  int v = (tid < nb) ? bsums[tid] : 0;
  int s = v;
#pragma unroll
  for (int o = 1; o < 64; o <<= 1) { int t = __shfl_up(s, o, 64); if (lane >= o) s += t; }
  if (lane == 63) wsum[wid] = s;
  __syncthreads();
  if (tid == 0) {
    int a = 0;
#pragma unroll
    for (int w = 0; w < 4; ++w) { a += wsum[w]; wsum[w] = a; }
  }
  __syncthreads();
  int base = (wid > 0) ? wsum[wid - 1] : 0;
  if (tid < nb) bsums[tid] = base + s - v;
  if (tid == 0) offs[n] = etot;
}

__global__ __launch_bounds__(256) void k_scan3(int* __restrict__ offs, int* __restrict__ cursor,
                                               const int* __restrict__ bsums, int n) {
  int i = blockIdx.x * 256 + threadIdx.x;
  if (i < n) {
    int o = offs[i] + bsums[blockIdx.x];
    offs[i] = o;
    cursor[i] = o;
  }
}

__global__ void k_fill(const int* __restrict__ ei, const int* __restrict__ flag,
                       int* __restrict__ cursor, int* __restrict__ ssrc,
                       int* __restrict__ sdst) {
  int e = blockIdx.x * 256 + threadIdx.x;
  if (e < N_EDGES) {
    int f = *flag;
    int s = clampN(ei[(size_t)e << f]);
    int d = clampN(ei[(size_t)(N_EDGES + e) << f]);
    int p = atomicAdd(&cursor[d], 1);
    if ((unsigned)p < (unsigned)N_EDGES) { ssrc[p] = s; sdst[p] = d; }
  }
}

// edge-parallel score: e[p] = leakyrelu(as[src] + ad[dst])  (CSR order)
__global__ void k_score(const int* __restrict__ ssrc, const int* __restrict__ sdst,
                        const float* __restrict__ as_, const float* __restrict__ ad_,
                        float* __restrict__ esc) {
  int p = blockIdx.x * 256 + threadIdx.x;
  if (p < N_EDGES) {
    float v = as_[clampN(ssrc[p])] + ad_[clampN(sdst[p])];
    esc[p] = v > 0.f ? v : 0.2f * v;
  }
}

// layer-1 aggregation: 4 edge-slots x 16 lanes, 8 ch/lane; fused relu(agg+b1+lin)
__global__ __launch_bounds__(256) void k_agg1(
    const int* __restrict__ offs, const int* __restrict__ ssrc,
    const float* __restrict__ esc, const unsigned short* __restrict__ hs1,
    const float* __restrict__ b1, unsigned short* __restrict__ linzb) {
  int node = (int)((blockIdx.x * 256 + threadIdx.x) >> 6);
  if (node >= N_NODES) return;
  int lane = threadIdx.x & 63;
  int g = lane >> 4, cl = lane & 15;
  int o0 = offs[node], o1 = offs[node + 1];
  if (!((unsigned)o0 <= (unsigned)N_EDGES && (unsigned)o1 <= (unsigned)N_EDGES && o0 <= o1))
    { o0 = 0; o1 = 0; }
  int deg = o1 - o0;
  float m = NEG_BIG;
  for (int j = g; j < deg; j += 4) m = fmaxf(m, esc[o0 + j]);
  m = fmaxf(m, __shfl_xor(m, 16, 64));
  m = fmaxf(m, __shfl_xor(m, 32, 64));
  float acc[8];
#pragma unroll
  for (int k = 0; k < 8; ++k) acc[k] = 0.f;
  float ssum = 0.f;
  for (int j = g; j < deg; j += 4) {
    float w = __expf(esc[o0 + j] - m);
    int s = clampN(ssrc[o0 + j]);
    uint4 hv = *(const uint4*)(hs1 + (size_t)s * 128 + cl * 8);
    ssum += w;
    acc[0] += w * __uint_as_float(hv.x << 16);
    acc[1] += w * __uint_as_float(hv.x & 0xffff0000u);
    acc[2] += w * __uint_as_float(hv.y << 16);
    acc[3] += w * __uint_as_float(hv.y & 0xffff0000u);
    acc[4] += w * __uint_as_float(hv.z << 16);
    acc[5] += w * __uint_as_float(hv.z & 0xffff0000u);
    acc[6] += w * __uint_as_float(hv.w << 16);
    acc[7] += w * __uint_as_float(hv.w & 0xffff0000u);
  }
  ssum += __shfl_xor(ssum, 16, 64);
  ssum += __shfl_xor(ssum, 32, 64);
#pragma unroll
  for (int k = 0; k < 8; ++k) {
    acc[k] += __shfl_xor(acc[k], 16, 64);
    acc[k] += __shfl_xor(acc[k], 32, 64);
  }
  if (g == 0) {
    float inv = 1.f / (ssum + 1e-16f);
    uint4 lv = *(const uint4*)(linzb + (size_t)node * 128 + cl * 8);
    float4 ba = *(const float4*)(b1 + cl * 8);
    float4 bb = *(const float4*)(b1 + cl * 8 + 4);
    float z[8];
    z[0] = acc[0] * inv + ba.x + __uint_as_float(lv.x << 16);
    z[1] = acc[1] * inv + ba.y + __uint_as_float(lv.x & 0xffff0000u);
    z[2] = acc[2] * inv + ba.z + __uint_as_float(lv.y << 16);
    z[3] = acc[3] * inv + ba.w + __uint_as_float(lv.y & 0xffff0000u);
    z[4] = acc[4] * inv + bb.x + __uint_as_float(lv.z << 16);
    z[5] = acc[5] * inv + bb.y + __uint_as_float(lv.z & 0xffff0000u);
    z[6] = acc[6] * inv + bb.z + __uint_as_float(lv.w << 16);
    z[7] = acc[7] * inv + bb.w + __uint_as_float(lv.w & 0xffff0000u);
#pragma unroll
    for (int k = 0; k < 8; ++k) z[k] = z[k] > 0.f ? z[k] : 0.f;
    uint4 ov;
    ov.x = (unsigned)f2bf(z[0]) | ((unsigned)f2bf(z[1]) << 16);
    ov.y = (unsigned)f2bf(z[2]) | ((unsigned)f2bf(z[3]) << 16);
    ov.z = (unsigned)f2bf(z[4]) | ((unsigned)f2bf(z[5]) << 16);
    ov.w = (unsigned)f2bf(z[6]) | ((unsigned)f2bf(z[7]) << 16);
    *(uint4*)(linzb + (size_t)node * 128 + cl * 8) = ov;
  }
}

// layer-2 aggregation: 8 edge-slots x 8 lanes, 8 ch/lane; fp32 out (+b2)
__global__ __launch_bounds__(256) void k_agg2(
    const int* __restrict__ offs, const int* __restrict__ ssrc,
    const float* __restrict__ esc, const unsigned short* __restrict__ hs2,
    const float* __restrict__ b2, float* __restrict__ out) {
  int node = (int)((blockIdx.x * 256 + threadIdx.x) >> 6);
  if (node >= N_NODES) return;
  int lane = threadIdx.x & 63;
  int g = lane >> 3, cl = lane & 7;
  int o0 = offs[node], o1 = offs[node + 1];
  if (!((unsigned)o0 <= (unsigned)N_EDGES && (unsigned)o1 <= (unsigned)N_EDGES && o0 <= o1))
    { o0 = 0; o1 = 0; }
  int deg = o1 - o0;
  float m = NEG_BIG;
  for (int j = g; j < deg; j += 8) m = fmaxf(m, esc[o0 + j]);
  m = fmaxf(m, __shfl_xor(m, 8, 64));
  m = fmaxf(m, __shfl_xor(m, 16, 64));
  m = fmaxf(m, __shfl_xor(m, 32, 64));
  float acc[8];
#pragma unroll
  for (int k = 0; k < 8; ++k) acc[k] = 0.f;
  float ssum = 0.f;
  for (int j = g; j < deg; j += 8) {
    float w = __expf(esc[o0 + j] - m);
    int s = clampN(ssrc[o0 + j]);
    uint4 hv = *(const uint4*)(hs2 + (size_t)s * 64 + cl * 8);
    ssum += w;
    acc[0] += w * __uint_as_float(hv.x << 16);
    acc[1] += w * __uint_as_float(hv.x & 0xffff0000u);
    acc[2] += w * __uint_as_float(hv.y << 16);
    acc[3] += w * __uint_as_float(hv.y & 0xffff0000u);
    acc[4] += w * __uint_as_float(hv.z << 16);
    acc[5] += w * __uint_as_float(hv.z & 0xffff0000u);
    acc[6] += w * __uint_as_float(hv.w << 16);
    acc[7] += w * __uint_as_float(hv.w & 0xffff0000u);
  }
  ssum += __shfl_xor(ssum, 8, 64);
  ssum += __shfl_xor(ssum, 16, 64);
  ssum += __shfl_xor(ssum, 32, 64);
#pragma unroll
  for (int k = 0; k < 8; ++k) {
    acc[k] += __shfl_xor(acc[k], 8, 64);
    acc[k] += __shfl_xor(acc[k], 16, 64);
    acc[k] += __shfl_xor(acc[k], 32, 64);
  }
  if (g == 0) {
    float inv = 1.f / (ssum + 1e-16f);
    float4 ba = *(const float4*)(b2 + cl * 8);
    float4 bb = *(const float4*)(b2 + cl * 8 + 4);
    float4 oa, ob;
    oa.x = acc[0] * inv + ba.x;
    oa.y = acc[1] * inv + ba.y;
    oa.z = acc[2] * inv + ba.z;
    oa.w = acc[3] * inv + ba.w;
    ob.x = acc[4] * inv + bb.x;
    ob.y = acc[5] * inv + bb.y;
    ob.z = acc[6] * inv + bb.z;
    ob.w = acc[7] * inv + bb.w;
    *(float4*)(out + (size_t)node * 64 + cl * 8) = oa;
    *(float4*)(out + (size_t)node * 64 + cl * 8 + 4) = ob;
  }
}

extern "C" void kernel_launch(void* const* d_in, const int* in_sizes, int n_in,
                              void* d_out, int out_size, void* d_ws, size_t ws_size,
                              hipStream_t stream) {
  (void)in_sizes; (void)n_in;
  const float* x      = (const float*)d_in[0];
  const int*   ei     = (const int*)d_in[1];
  const float* lin1_w = (const float*)d_in[2];
  const float* lin1_b = (const float*)d_in[3];
  const float* w1_src = (const float*)d_in[4];
  const float* w1_dst = (const float*)d_in[5];
  const float* a1_src = (const float*)d_in[6];
  const float* a1_dst = (const float*)d_in[7];
  const float* b1     = (const float*)d_in[8];
  const float* w2_src = (const float*)d_in[9];
  const float* w2_dst = (const float*)d_in[10];
  const float* a2_src = (const float*)d_in[11];
  const float* a2_dst = (const float*)d_in[12];
  const float* b2     = (const float*)d_in[13];
  float* out = (float*)d_out;

  char* ws = (char*)d_ws;
  size_t off = 0;
  auto alloc = [&](size_t bytes) -> void* {
    void* p = ws + off;
    off += (bytes + 255) & ~(size_t)255;
    return p;
  };
  int* flag    = (int*)alloc(256);
  float* c1dst = (float*)alloc(128 * 4);
  float* c2dst = (float*)alloc(128 * 4);
  int* deg     = (int*)alloc((size_t)N_NODES * 4);
  int* offs    = (int*)alloc((size_t)(N_NODES + 1) * 4);
  int* cursor  = (int*)alloc((size_t)N_NODES * 4);
  int* bsums   = (int*)alloc(1024);
  float* as1   = (float*)alloc((size_t)N_NODES * 4);
  float* ad1   = (float*)alloc((size_t)N_NODES * 4);
  float* as2   = (float*)alloc((size_t)N_NODES * 4);
  float* ad2   = (float*)alloc((size_t)N_NODES * 4);
  int* ssrc    = (int*)alloc((size_t)N_EDGES * 4);
  int* sdst    = (int*)alloc((size_t)N_EDGES * 4);
  float* esc   = (float*)alloc((size_t)N_EDGES * 4);
  unsigned short* hs1   = (unsigned short*)alloc((size_t)N_NODES * 128 * 2);
  unsigned short* hs2   = (unsigned short*)alloc((size_t)N_NODES * 64 * 2);
  unsigned short* linzb = (unsigned short*)alloc((size_t)N_NODES * 128 * 2);

  if (off > ws_size) {
    k_zero_out<<<(out_size + 255) / 256, 256, 0, stream>>>(out, out_size);
    return;
  }

  int ebl = (N_EDGES + 255) / 256;   // 3125
  int nbl = (N_NODES + 3) / 4;       // 12500
  hipMemsetAsync(deg, 0, (size_t)N_NODES * 4, stream);
  k_detect<<<1, 64, 0, stream>>>(ei, flag);
  k_precompute<<<1, 128, 0, stream>>>(w1_dst, a1_dst, w2_dst, a2_dst, c1dst, c2dst);
  k_gemm1<<<N_NODES / 16, 256, 0, stream>>>(x, w1_src, lin1_w, lin1_b, hs1, linzb);
  k_alpha<128, false><<<nbl, 256, 0, stream>>>(hs1, a1_src, x, c1dst, as1, ad1);
  k_count<<<ebl, 256, 0, stream>>>(ei, flag, deg);
  int nb = (N_NODES + 255) / 256;    // 196
  k_scan1<<<nb, 256, 0, stream>>>(deg, offs, bsums, N_NODES);
  k_scan2<<<1, 256, 0, stream>>>(bsums, nb, offs, N_NODES, N_EDGES);
  k_scan3<<<nb, 256, 0, stream>>>(offs, cursor, bsums, N_NODES);
  k_fill<<<ebl, 256, 0, stream>>>(ei, flag, cursor, ssrc, sdst);
  k_score<<<ebl, 256, 0, stream>>>(ssrc, sdst, as1, ad1, esc);
  k_agg1<<<nbl, 256, 0, stream>>>(offs, ssrc, esc, hs1, b1, linzb);
  k_gemm2<<<N_NODES / 16, 256, 0, stream>>>(linzb, w2_src, hs2);
  k_alpha<64, true><<<nbl, 256, 0, stream>>>(hs2, a2_src, linzb, c2dst, as2, ad2);
  k_score<<<ebl, 256, 0, stream>>>(ssrc, sdst, as2, ad2, esc);
  k_agg2<<<nbl, 256, 0, stream>>>(offs, ssrc, esc, hs2, b2, out);
}

// Round 5
// 259.208 us; speedup vs baseline: 1.5278x; 1.1456x over previous
//
#include <hip/hip_runtime.h>

static constexpr int N_NODES = 50000;
static constexpr int N_EDGES = 800000;
static constexpr float NEG_BIG = -3.0e38f;

typedef __attribute__((ext_vector_type(8))) short bf16x8;
typedef __attribute__((ext_vector_type(4))) float f32x4;

__device__ __forceinline__ float bf2f(unsigned short u) {
  union { unsigned int i; float f; } v; v.i = ((unsigned int)u) << 16; return v.f;
}
__device__ __forceinline__ unsigned short f2bf(float f) {
  union { unsigned int i; float f; } v; v.f = f;
  unsigned int r = (v.i + 0x7fffu + ((v.i >> 16) & 1u)) >> 16;
  return (unsigned short)r;
}
__device__ __forceinline__ int clampN(int v) {
  unsigned u = (unsigned)v; return (u < (unsigned)N_NODES) ? (int)u : 0;
}

__global__ void k_detect(const int* __restrict__ ei, int* __restrict__ flag) {
  if (threadIdx.x == 0 && blockIdx.x == 0) {
    int z = ei[1] | ei[3] | ei[5] | ei[7];
    *flag = (z == 0) ? 1 : 0;
  }
}

__global__ void k_zero_out(float* __restrict__ out, int n) {
  int i = blockIdx.x * 256 + threadIdx.x;
  if (i < n) out[i] = 0.f;
}

// c_dst[k] = sum_c w_dst[k][c] * a_dst[c]
__global__ void k_precompute(const float* __restrict__ w1_dst, const float* __restrict__ a1_dst,
                             const float* __restrict__ w2_dst, const float* __restrict__ a2_dst,
                             float* __restrict__ c1dst, float* __restrict__ c2dst) {
  int k = threadIdx.x;
  if (k < 128) {
    float s1 = 0.f;
    for (int c = 0; c < 128; ++c) s1 += w1_dst[k * 128 + c] * a1_dst[c];
    c1dst[k] = s1;
    float s2 = 0.f;
    for (int c = 0; c < 64; ++c) s2 += w2_dst[k * 64 + c] * a2_dst[c];
    c2dst[k] = s2;
  }
}

// weights -> bf16, transposed to [col][k] for MFMA B-fragments
__global__ void k_prepw(const float* __restrict__ w1_src, const float* __restrict__ wlin,
                        const float* __restrict__ w2_src,
                        unsigned short* __restrict__ w1T, unsigned short* __restrict__ w2T) {
  int idx = blockIdx.x * 256 + threadIdx.x;
  if (idx < 256 * 128) {
    int c = idx >> 7, k = idx & 127;
    float v = (c < 128) ? w1_src[k * 128 + c] : wlin[k * 128 + (c - 128)];
    w1T[idx] = f2bf(v);
  } else if (idx < 256 * 128 + 64 * 128) {
    int r = idx - 256 * 128;
    int c = r >> 7, k = r & 127;
    w2T[r] = f2bf(w2_src[k * 64 + c]);
  }
}

// MFMA GEMM1: [16 rows/block] x @ {w1_src|lin1_w} -> hs1, linzb(+lin1_b), bf16 out
__global__ __launch_bounds__(256) void k_gemm1(
    const float* __restrict__ x, const unsigned short* __restrict__ w1T,
    const float* __restrict__ lin_b,
    unsigned short* __restrict__ hs1, unsigned short* __restrict__ linzb) {
  __shared__ unsigned char aLds[16 * 256];  // [16][128] bf16, XOR-swizzled
  int nb = blockIdx.x * 16;
  int tid = threadIdx.x;
#pragma unroll
  for (int i = 0; i < 2; ++i) {
    int t = tid + i * 256;
    int row = t >> 5, q = t & 31;  // q: float4 index
    float4 v = *(const float4*)(x + (size_t)(nb + row) * 128 + q * 4);
    unsigned int lo = (unsigned)f2bf(v.x) | ((unsigned)f2bf(v.y) << 16);
    unsigned int hi = (unsigned)f2bf(v.z) | ((unsigned)f2bf(v.w) << 16);
    int kb = (q * 8) ^ ((row & 7) << 4);
    *(uint2*)(aLds + row * 256 + kb) = make_uint2(lo, hi);
  }
  __syncthreads();
  int wv = tid >> 6, l = tid & 63;
  int lrow = l & 15, lk = l >> 4;
  bf16x8 bfrag[4][4];
#pragma unroll
  for (int ct = 0; ct < 4; ++ct) {
    int col = wv * 64 + ct * 16 + lrow;
#pragma unroll
    for (int ks = 0; ks < 4; ++ks)
      bfrag[ct][ks] = *(const bf16x8*)(w1T + (size_t)col * 128 + ks * 32 + lk * 8);
  }
  f32x4 acc[4] = {{0.f,0.f,0.f,0.f},{0.f,0.f,0.f,0.f},{0.f,0.f,0.f,0.f},{0.f,0.f,0.f,0.f}};
#pragma unroll
  for (int ks = 0; ks < 4; ++ks) {
    int kb = (ks * 64 + lk * 16) ^ ((lrow & 7) << 4);
    bf16x8 afrag = *(const bf16x8*)(aLds + lrow * 256 + kb);
#pragma unroll
    for (int ct = 0; ct < 4; ++ct)
      acc[ct] = __builtin_amdgcn_mfma_f32_16x16x32_bf16(afrag, bfrag[ct][ks], acc[ct], 0, 0, 0);
  }
#pragma unroll
  for (int ct = 0; ct < 4; ++ct) {
    int col = wv * 64 + ct * 16 + lrow;
#pragma unroll
    for (int j = 0; j < 4; ++j) {
      int row = nb + lk * 4 + j;
      float v = acc[ct][j];
      if (col < 128) hs1[(size_t)row * 128 + col] = f2bf(v);
      else linzb[(size_t)row * 128 + (col - 128)] = f2bf(v + lin_b[col - 128]);
    }
  }
}

// MFMA GEMM2: [64 rows/block] zb(bf16) @ w2_src -> hs2 bf16
__global__ __launch_bounds__(256) void k_gemm2(
    const unsigned short* __restrict__ zb, const unsigned short* __restrict__ w2T,
    unsigned short* __restrict__ hs2) {
  __shared__ unsigned char aLds[64 * 256];  // [64][128] bf16, XOR-swizzled
  int nb = blockIdx.x * 64;
  int tid = threadIdx.x;
#pragma unroll
  for (int i = 0; i < 4; ++i) {
    int t = tid + i * 256;
    int row = t >> 4, q = t & 15;  // 16-byte units
    int grow = nb + row; if (grow >= N_NODES) grow = N_NODES - 1;
    uint4 v = *(const uint4*)(zb + (size_t)grow * 128 + q * 8);
    int kb = (q * 16) ^ ((row & 7) << 4);
    *(uint4*)(aLds + row * 256 + kb) = v;
  }
  __syncthreads();
  int wv = tid >> 6, l = tid & 63;
  int lrow = l & 15, lk = l >> 4;
  bf16x8 bfrag[4][4];
#pragma unroll
  for (int ct = 0; ct < 4; ++ct) {
    int col = ct * 16 + lrow;
#pragma unroll
    for (int ks = 0; ks < 4; ++ks)
      bfrag[ct][ks] = *(const bf16x8*)(w2T + (size_t)col * 128 + ks * 32 + lk * 8);
  }
  f32x4 acc[4] = {{0.f,0.f,0.f,0.f},{0.f,0.f,0.f,0.f},{0.f,0.f,0.f,0.f},{0.f,0.f,0.f,0.f}};
  int arow = wv * 16 + lrow;
#pragma unroll
  for (int ks = 0; ks < 4; ++ks) {
    int kb = (ks * 64 + lk * 16) ^ ((arow & 7) << 4);
    bf16x8 afrag = *(const bf16x8*)(aLds + arow * 256 + kb);
#pragma unroll
    for (int ct = 0; ct < 4; ++ct)
      acc[ct] = __builtin_amdgcn_mfma_f32_16x16x32_bf16(afrag, bfrag[ct][ks], acc[ct], 0, 0, 0);
  }
#pragma unroll
  for (int ct = 0; ct < 4; ++ct) {
    int col = ct * 16 + lrow;
#pragma unroll
    for (int j = 0; j < 4; ++j) {
      int row = nb + wv * 16 + lk * 4 + j;
      if (row < N_NODES) hs2[(size_t)row * 64 + col] = f2bf(acc[ct][j]);
    }
  }
}

// as[n] = hs[n].asrc ; ad[n] = xin[n].cdst   (one wave per node)
template <int C, bool XBF>
__global__ __launch_bounds__(256) void k_alpha(
    const unsigned short* __restrict__ hs, const float* __restrict__ asrc,
    const void* __restrict__ xin, const float* __restrict__ cdst,
    float* __restrict__ as_, float* __restrict__ ad_) {
  int node = (int)((blockIdx.x * 256 + threadIdx.x) >> 6);
  if (node >= N_NODES) return;
  int lane = threadIdx.x & 63;
  float sa = 0.f;
#pragma unroll
  for (int k = lane; k < C; k += 64) sa += bf2f(hs[(size_t)node * C + k]) * asrc[k];
  float sd = 0.f;
  if (XBF) {
    const unsigned short* xb = (const unsigned short*)xin;
#pragma unroll
    for (int k = lane; k < 128; k += 64) sd += bf2f(xb[(size_t)node * 128 + k]) * cdst[k];
  } else {
    const float* xf = (const float*)xin;
#pragma unroll
    for (int k = lane; k < 128; k += 64) sd += xf[(size_t)node * 128 + k] * cdst[k];
  }
#pragma unroll
  for (int o = 32; o > 0; o >>= 1) {
    sa += __shfl_xor(sa, o, 64);
    sd += __shfl_xor(sd, o, 64);
  }
  if (lane == 0) { as_[node] = sa; ad_[node] = sd; }
}

__global__ void k_count(const int* __restrict__ ei, const int* __restrict__ flag,
                        int* __restrict__ deg) {
  int e = blockIdx.x * 256 + threadIdx.x;
  if (e < N_EDGES) {
    int f = *flag;
    int d = clampN(ei[(size_t)(N_EDGES + e) << f]);
    atomicAdd(&deg[d], 1);
  }
}

__global__ __launch_bounds__(256) void k_scan1(const int* __restrict__ deg,
                                               int* __restrict__ offs,
                                               int* __restrict__ bsums, int n) {
  __shared__ int wsum[4];
  int i = blockIdx.x * 256 + threadIdx.x;
  int lane = threadIdx.x & 63, wid = threadIdx.x >> 6;
  int v = (i < n) ? deg[i] : 0;
  int s = v;
#pragma unroll
  for (int o = 1; o < 64; o <<= 1) { int t = __shfl_up(s, o, 64); if (lane >= o) s += t; }
  if (lane == 63) wsum[wid] = s;
  __syncthreads();
  if (threadIdx.x == 0) {
    int a = 0;
#pragma unroll
    for (int w = 0; w < 4; ++w) { a += wsum[w]; wsum[w] = a; }
  }
  __syncthreads();
  int base = (wid > 0) ? wsum[wid - 1] : 0;
  if (i < n) offs[i] = base + s - v;
  if (threadIdx.x == 0) bsums[blockIdx.x] = wsum[3];
}

__global__ __launch_bounds__(256) void k_scan2(int* __restrict__ bsums, int nb,
                                               int* __restrict__ offs, int n, int etot) {
  __shared__ int wsum[4];
  int tid = threadIdx.x, lane = tid & 63, wid = tid >> 6;
  int v = (tid < nb) ? bsums[tid] : 0;
  int s = v;
#pragma unroll
  for (int o = 1; o < 64; o <<= 1) { int t = __shfl_up(s, o, 64); if (lane >= o) s += t; }
  if (lane == 63) wsum[wid] = s;
  __syncthreads();
  if (tid == 0) {
    int a = 0;
#pragma unroll
    for (int w = 0; w < 4; ++w) { a += wsum[w]; wsum[w] = a; }
  }
  __syncthreads();
  int base = (wid > 0) ? wsum[wid - 1] : 0;
  if (tid < nb) bsums[tid] = base + s - v;
  if (tid == 0) offs[n] = etot;
}

__global__ __launch_bounds__(256) void k_scan3(int* __restrict__ offs, int* __restrict__ cursor,
                                               const int* __restrict__ bsums, int n) {
  int i = blockIdx.x * 256 + threadIdx.x;
  if (i < n) {
    int o = offs[i] + bsums[blockIdx.x];
    offs[i] = o;
    cursor[i] = o;
  }
}

__global__ void k_fill(const int* __restrict__ ei, const int* __restrict__ flag,
                       int* __restrict__ cursor, int* __restrict__ ssrc,
                       int* __restrict__ sdst) {
  int e = blockIdx.x * 256 + threadIdx.x;
  if (e < N_EDGES) {
    int f = *flag;
    int s = clampN(ei[(size_t)e << f]);
    int d = clampN(ei[(size_t)(N_EDGES + e) << f]);
    int p = atomicAdd(&cursor[d], 1);
    if ((unsigned)p < (unsigned)N_EDGES) { ssrc[p] = s; sdst[p] = d; }
  }
}

// edge-parallel score: e[p] = leakyrelu(as[src] + ad[dst])  (CSR order)
__global__ void k_score(const int* __restrict__ ssrc, const int* __restrict__ sdst,
                        const float* __restrict__ as_, const float* __restrict__ ad_,
                        float* __restrict__ esc) {
  int p = blockIdx.x * 256 + threadIdx.x;
  if (p < N_EDGES) {
    float v = as_[clampN(ssrc[p])] + ad_[clampN(sdst[p])];
    esc[p] = v > 0.f ? v : 0.2f * v;
  }
}

// layer-1 aggregation: 4 edge-slots x 16 lanes, 8 ch/lane; fused relu(agg+b1+lin)
__global__ __launch_bounds__(256) void k_agg1(
    const int* __restrict__ offs, const int* __restrict__ ssrc,
    const float* __restrict__ esc, const unsigned short* __restrict__ hs1,
    const float* __restrict__ b1, unsigned short* __restrict__ linzb) {
  int node = (int)((blockIdx.x * 256 + threadIdx.x) >> 6);
  if (node >= N_NODES) return;
  int lane = threadIdx.x & 63;
  int g = lane >> 4, cl = lane & 15;
  int o0 = offs[node], o1 = offs[node + 1];
  if (!((unsigned)o0 <= (unsigned)N_EDGES && (unsigned)o1 <= (unsigned)N_EDGES && o0 <= o1))
    { o0 = 0; o1 = 0; }
  int deg = o1 - o0;
  float m = NEG_BIG;
  for (int j = g; j < deg; j += 4) m = fmaxf(m, esc[o0 + j]);
  m = fmaxf(m, __shfl_xor(m, 16, 64));
  m = fmaxf(m, __shfl_xor(m, 32, 64));
  float acc[8];
#pragma unroll
  for (int k = 0; k < 8; ++k) acc[k] = 0.f;
  float ssum = 0.f;
  for (int j = g; j < deg; j += 4) {
    float w = __expf(esc[o0 + j] - m);
    int s = clampN(ssrc[o0 + j]);
    uint4 hv = *(const uint4*)(hs1 + (size_t)s * 128 + cl * 8);
    ssum += w;
    acc[0] += w * __uint_as_float(hv.x << 16);
    acc[1] += w * __uint_as_float(hv.x & 0xffff0000u);
    acc[2] += w * __uint_as_float(hv.y << 16);
    acc[3] += w * __uint_as_float(hv.y & 0xffff0000u);
    acc[4] += w * __uint_as_float(hv.z << 16);
    acc[5] += w * __uint_as_float(hv.z & 0xffff0000u);
    acc[6] += w * __uint_as_float(hv.w << 16);
    acc[7] += w * __uint_as_float(hv.w & 0xffff0000u);
  }
  ssum += __shfl_xor(ssum, 16, 64);
  ssum += __shfl_xor(ssum, 32, 64);
#pragma unroll
  for (int k = 0; k < 8; ++k) {
    acc[k] += __shfl_xor(acc[k], 16, 64);
    acc[k] += __shfl_xor(acc[k], 32, 64);
  }
  if (g == 0) {
    float inv = 1.f / (ssum + 1e-16f);
    uint4 lv = *(const uint4*)(linzb + (size_t)node * 128 + cl * 8);
    float4 ba = *(const float4*)(b1 + cl * 8);
    float4 bb = *(const float4*)(b1 + cl * 8 + 4);
    float z[8];
    z[0] = acc[0] * inv + ba.x + __uint_as_float(lv.x << 16);
    z[1] = acc[1] * inv + ba.y + __uint_as_float(lv.x & 0xffff0000u);
    z[2] = acc[2] * inv + ba.z + __uint_as_float(lv.y << 16);
    z[3] = acc[3] * inv + ba.w + __uint_as_float(lv.y & 0xffff0000u);
    z[4] = acc[4] * inv + bb.x + __uint_as_float(lv.z << 16);
    z[5] = acc[5] * inv + bb.y + __uint_as_float(lv.z & 0xffff0000u);
    z[6] = acc[6] * inv + bb.z + __uint_as_float(lv.w << 16);
    z[7] = acc[7] * inv + bb.w + __uint_as_float(lv.w & 0xffff0000u);
#pragma unroll
    for (int k = 0; k < 8; ++k) z[k] = z[k] > 0.f ? z[k] : 0.f;
    uint4 ov;
    ov.x = (unsigned)f2bf(z[0]) | ((unsigned)f2bf(z[1]) << 16);
    ov.y = (unsigned)f2bf(z[2]) | ((unsigned)f2bf(z[3]) << 16);
    ov.z = (unsigned)f2bf(z[4]) | ((unsigned)f2bf(z[5]) << 16);
    ov.w = (unsigned)f2bf(z[6]) | ((unsigned)f2bf(z[7]) << 16);
    *(uint4*)(linzb + (size_t)node * 128 + cl * 8) = ov;
  }
}

// layer-2 aggregation: 8 edge-slots x 8 lanes, 8 ch/lane; fp32 out (+b2)
__global__ __launch_bounds__(256) void k_agg2(
    const int* __restrict__ offs, const int* __restrict__ ssrc,
    const float* __restrict__ esc, const unsigned short* __restrict__ hs2,
    const float* __restrict__ b2, float* __restrict__ out) {
  int node = (int)((blockIdx.x * 256 + threadIdx.x) >> 6);
  if (node >= N_NODES) return;
  int lane = threadIdx.x & 63;
  int g = lane >> 3, cl = lane & 7;
  int o0 = offs[node], o1 = offs[node + 1];
  if (!((unsigned)o0 <= (unsigned)N_EDGES && (unsigned)o1 <= (unsigned)N_EDGES && o0 <= o1))
    { o0 = 0; o1 = 0; }
  int deg = o1 - o0;
  float m = NEG_BIG;
  for (int j = g; j < deg; j += 8) m = fmaxf(m, esc[o0 + j]);
  m = fmaxf(m, __shfl_xor(m, 8, 64));
  m = fmaxf(m, __shfl_xor(m, 16, 64));
  m = fmaxf(m, __shfl_xor(m, 32, 64));
  float acc[8];
#pragma unroll
  for (int k = 0; k < 8; ++k) acc[k] = 0.f;
  float ssum = 0.f;
  for (int j = g; j < deg; j += 8) {
    float w = __expf(esc[o0 + j] - m);
    int s = clampN(ssrc[o0 + j]);
    uint4 hv = *(const uint4*)(hs2 + (size_t)s * 64 + cl * 8);
    ssum += w;
    acc[0] += w * __uint_as_float(hv.x << 16);
    acc[1] += w * __uint_as_float(hv.x & 0xffff0000u);
    acc[2] += w * __uint_as_float(hv.y << 16);
    acc[3] += w * __uint_as_float(hv.y & 0xffff0000u);
    acc[4] += w * __uint_as_float(hv.z << 16);
    acc[5] += w * __uint_as_float(hv.z & 0xffff0000u);
    acc[6] += w * __uint_as_float(hv.w << 16);
    acc[7] += w * __uint_as_float(hv.w & 0xffff0000u);
  }
  ssum += __shfl_xor(ssum, 8, 64);
  ssum += __shfl_xor(ssum, 16, 64);
  ssum += __shfl_xor(ssum, 32, 64);
#pragma unroll
  for (int k = 0; k < 8; ++k) {
    acc[k] += __shfl_xor(acc[k], 8, 64);
    acc[k] += __shfl_xor(acc[k], 16, 64);
    acc[k] += __shfl_xor(acc[k], 32, 64);
  }
  if (g == 0) {
    float inv = 1.f / (ssum + 1e-16f);
    float4 ba = *(const float4*)(b2 + cl * 8);
    float4 bb = *(const float4*)(b2 + cl * 8 + 4);
    float4 oa, ob;
    oa.x = acc[0] * inv + ba.x;
    oa.y = acc[1] * inv + ba.y;
    oa.z = acc[2] * inv + ba.z;
    oa.w = acc[3] * inv + ba.w;
    ob.x = acc[4] * inv + bb.x;
    ob.y = acc[5] * inv + bb.y;
    ob.z = acc[6] * inv + bb.z;
    ob.w = acc[7] * inv + bb.w;
    *(float4*)(out + (size_t)node * 64 + cl * 8) = oa;
    *(float4*)(out + (size_t)node * 64 + cl * 8 + 4) = ob;
  }
}

extern "C" void kernel_launch(void* const* d_in, const int* in_sizes, int n_in,
                              void* d_out, int out_size, void* d_ws, size_t ws_size,
                              hipStream_t stream) {
  (void)in_sizes; (void)n_in;
  const float* x      = (const float*)d_in[0];
  const int*   ei     = (const int*)d_in[1];
  const float* lin1_w = (const float*)d_in[2];
  const float* lin1_b = (const float*)d_in[3];
  const float* w1_src = (const float*)d_in[4];
  const float* w1_dst = (const float*)d_in[5];
  const float* a1_src = (const float*)d_in[6];
  const float* a1_dst = (const float*)d_in[7];
  const float* b1     = (const float*)d_in[8];
  const float* w2_src = (const float*)d_in[9];
  const float* w2_dst = (const float*)d_in[10];
  const float* a2_src = (const float*)d_in[11];
  const float* a2_dst = (const float*)d_in[12];
  const float* b2     = (const float*)d_in[13];
  float* out = (float*)d_out;

  char* ws = (char*)d_ws;
  size_t off = 0;
  auto alloc = [&](size_t bytes) -> void* {
    void* p = ws + off;
    off += (bytes + 255) & ~(size_t)255;
    return p;
  };
  int* flag    = (int*)alloc(256);
  float* c1dst = (float*)alloc(128 * 4);
  float* c2dst = (float*)alloc(128 * 4);
  unsigned short* w1T = (unsigned short*)alloc(256 * 128 * 2);
  unsigned short* w2T = (unsigned short*)alloc(64 * 128 * 2);
  int* deg     = (int*)alloc((size_t)N_NODES * 4);
  int* offs    = (int*)alloc((size_t)(N_NODES + 1) * 4);
  int* cursor  = (int*)alloc((size_t)N_NODES * 4);
  int* bsums   = (int*)alloc(1024);
  float* as1   = (float*)alloc((size_t)N_NODES * 4);
  float* ad1   = (float*)alloc((size_t)N_NODES * 4);
  float* as2   = (float*)alloc((size_t)N_NODES * 4);
  float* ad2   = (float*)alloc((size_t)N_NODES * 4);
  int* ssrc    = (int*)alloc((size_t)N_EDGES * 4);
  int* sdst    = (int*)alloc((size_t)N_EDGES * 4);
  float* esc   = (float*)alloc((size_t)N_EDGES * 4);
  unsigned short* hs1   = (unsigned short*)alloc((size_t)N_NODES * 128 * 2);
  unsigned short* hs2   = (unsigned short*)alloc((size_t)N_NODES * 64 * 2);
  unsigned short* linzb = (unsigned short*)alloc((size_t)N_NODES * 128 * 2);

  if (off > ws_size) {
    k_zero_out<<<(out_size + 255) / 256, 256, 0, stream>>>(out, out_size);
    return;
  }

  int ebl = (N_EDGES + 255) / 256;   // 3125
  int nbl = (N_NODES + 3) / 4;       // 12500
  hipMemsetAsync(deg, 0, (size_t)N_NODES * 4, stream);
  k_detect<<<1, 64, 0, stream>>>(ei, flag);
  k_precompute<<<1, 128, 0, stream>>>(w1_dst, a1_dst, w2_dst, a2_dst, c1dst, c2dst);
  k_prepw<<<160, 256, 0, stream>>>(w1_src, lin1_w, w2_src, w1T, w2T);
  k_gemm1<<<N_NODES / 16, 256, 0, stream>>>(x, w1T, lin1_b, hs1, linzb);
  k_alpha<128, false><<<nbl, 256, 0, stream>>>(hs1, a1_src, x, c1dst, as1, ad1);
  k_count<<<ebl, 256, 0, stream>>>(ei, flag, deg);
  int nb = (N_NODES + 255) / 256;    // 196
  k_scan1<<<nb, 256, 0, stream>>>(deg, offs, bsums, N_NODES);
  k_scan2<<<1, 256, 0, stream>>>(bsums, nb, offs, N_NODES, N_EDGES);
  k_scan3<<<nb, 256, 0, stream>>>(offs, cursor, bsums, N_NODES);
  k_fill<<<ebl, 256, 0, stream>>>(ei, flag, cursor, ssrc, sdst);
  k_score<<<ebl, 256, 0, stream>>>(ssrc, sdst, as1, ad1, esc);
  k_agg1<<<nbl, 256, 0, stream>>>(offs, ssrc, esc, hs1, b1, linzb);
  k_gemm2<<<(N_NODES + 63) / 64, 256, 0, stream>>>(linzb, w2T, hs2);
  k_alpha<64, true><<<nbl, 256, 0, stream>>>(hs2, a2_src, linzb, c2dst, as2, ad2);
  k_score<<<ebl, 256, 0, stream>>>(ssrc, sdst, as2, ad2, esc);
  k_agg2<<<nbl, 256, 0, stream>>>(offs, ssrc, esc, hs2, b2, out);
}

// Round 6
// 223.076 us; speedup vs baseline: 1.7752x; 1.1620x over previous
//
#include <hip/hip_runtime.h>

static constexpr int N_NODES = 50000;
static constexpr int N_EDGES = 800000;
static constexpr int NPART = 8;               // XCD count
static constexpr int PART_SZ = N_NODES / NPART;  // 6250

typedef __attribute__((ext_vector_type(8))) short bf16x8;
typedef __attribute__((ext_vector_type(4))) float f32x4;

__device__ __forceinline__ float bf2f(unsigned short u) {
  union { unsigned int i; float f; } v; v.i = ((unsigned int)u) << 16; return v.f;
}
__device__ __forceinline__ unsigned short f2bf(float f) {
  union { unsigned int i; float f; } v; v.f = f;
  unsigned int r = (v.i + 0x7fffu + ((v.i >> 16) & 1u)) >> 16;
  return (unsigned short)r;
}
__device__ __forceinline__ int clampN(int v) {
  unsigned u = (unsigned)v; return (u < (unsigned)N_NODES) ? (int)u : 0;
}

__global__ void k_detect(const int* __restrict__ ei, int* __restrict__ flag) {
  if (threadIdx.x == 0 && blockIdx.x == 0) {
    int z = ei[1] | ei[3] | ei[5] | ei[7];
    *flag = (z == 0) ? 1 : 0;
  }
}

__global__ void k_zero_out(float* __restrict__ out, int n) {
  int i = blockIdx.x * 256 + threadIdx.x;
  if (i < n) out[i] = 0.f;
}

// weights -> bf16 [col][k]; block 160 also computes c_dst vectors
__global__ void k_prepw(const float* __restrict__ w1_src, const float* __restrict__ wlin,
                        const float* __restrict__ w2_src,
                        const float* __restrict__ w1_dst, const float* __restrict__ a1_dst,
                        const float* __restrict__ w2_dst, const float* __restrict__ a2_dst,
                        unsigned short* __restrict__ w1T, unsigned short* __restrict__ w2T,
                        float* __restrict__ c1dst, float* __restrict__ c2dst) {
  int idx = blockIdx.x * 256 + threadIdx.x;
  if (idx < 256 * 128) {
    int c = idx >> 7, k = idx & 127;
    float v = (c < 128) ? w1_src[k * 128 + c] : wlin[k * 128 + (c - 128)];
    w1T[idx] = f2bf(v);
  } else if (idx < 256 * 128 + 64 * 128) {
    int r = idx - 256 * 128;
    int c = r >> 7, k = r & 127;
    w2T[r] = f2bf(w2_src[k * 64 + c]);
  } else if (blockIdx.x == 160) {
    int k = threadIdx.x;
    if (k < 128) {
      float s1 = 0.f;
      for (int c = 0; c < 128; ++c) s1 += w1_dst[k * 128 + c] * a1_dst[c];
      c1dst[k] = s1;
      float s2 = 0.f;
      for (int c = 0; c < 64; ++c) s2 += w2_dst[k * 64 + c] * a2_dst[c];
      c2dst[k] = s2;
    }
  }
}

// MFMA GEMM1: [16 rows/block] x @ {w1_src|lin1_w} -> hs1, linzb(+lin1_b), bf16 out
__global__ __launch_bounds__(256) void k_gemm1(
    const float* __restrict__ x, const unsigned short* __restrict__ w1T,
    const float* __restrict__ lin_b,
    unsigned short* __restrict__ hs1, unsigned short* __restrict__ linzb) {
  __shared__ unsigned char aLds[16 * 256];
  int nb = blockIdx.x * 16;
  int tid = threadIdx.x;
#pragma unroll
  for (int i = 0; i < 2; ++i) {
    int t = tid + i * 256;
    int row = t >> 5, q = t & 31;
    float4 v = *(const float4*)(x + (size_t)(nb + row) * 128 + q * 4);
    unsigned int lo = (unsigned)f2bf(v.x) | ((unsigned)f2bf(v.y) << 16);
    unsigned int hi = (unsigned)f2bf(v.z) | ((unsigned)f2bf(v.w) << 16);
    int kb = (q * 8) ^ ((row & 7) << 4);
    *(uint2*)(aLds + row * 256 + kb) = make_uint2(lo, hi);
  }
  __syncthreads();
  int wv = tid >> 6, l = tid & 63;
  int lrow = l & 15, lk = l >> 4;
  bf16x8 bfrag[4][4];
#pragma unroll
  for (int ct = 0; ct < 4; ++ct) {
    int col = wv * 64 + ct * 16 + lrow;
#pragma unroll
    for (int ks = 0; ks < 4; ++ks)
      bfrag[ct][ks] = *(const bf16x8*)(w1T + (size_t)col * 128 + ks * 32 + lk * 8);
  }
  f32x4 acc[4] = {{0.f,0.f,0.f,0.f},{0.f,0.f,0.f,0.f},{0.f,0.f,0.f,0.f},{0.f,0.f,0.f,0.f}};
#pragma unroll
  for (int ks = 0; ks < 4; ++ks) {
    int kb = (ks * 64 + lk * 16) ^ ((lrow & 7) << 4);
    bf16x8 afrag = *(const bf16x8*)(aLds + lrow * 256 + kb);
#pragma unroll
    for (int ct = 0; ct < 4; ++ct)
      acc[ct] = __builtin_amdgcn_mfma_f32_16x16x32_bf16(afrag, bfrag[ct][ks], acc[ct], 0, 0, 0);
  }
#pragma unroll
  for (int ct = 0; ct < 4; ++ct) {
    int col = wv * 64 + ct * 16 + lrow;
#pragma unroll
    for (int j = 0; j < 4; ++j) {
      int row = nb + lk * 4 + j;
      float v = acc[ct][j];
      if (col < 128) hs1[(size_t)row * 128 + col] = f2bf(v);
      else linzb[(size_t)row * 128 + (col - 128)] = f2bf(v + lin_b[col - 128]);
    }
  }
}

// MFMA GEMM2: [64 rows/block] zb(bf16) @ w2_src -> hs2 bf16
__global__ __launch_bounds__(256) void k_gemm2(
    const unsigned short* __restrict__ zb, const unsigned short* __restrict__ w2T,
    unsigned short* __restrict__ hs2) {
  __shared__ unsigned char aLds[64 * 256];
  int nb = blockIdx.x * 64;
  int tid = threadIdx.x;
#pragma unroll
  for (int i = 0; i < 4; ++i) {
    int t = tid + i * 256;
    int row = t >> 4, q = t & 15;
    int grow = nb + row; if (grow >= N_NODES) grow = N_NODES - 1;
    uint4 v = *(const uint4*)(zb + (size_t)grow * 128 + q * 8);
    int kb = (q * 16) ^ ((row & 7) << 4);
    *(uint4*)(aLds + row * 256 + kb) = v;
  }
  __syncthreads();
  int wv = tid >> 6, l = tid & 63;
  int lrow = l & 15, lk = l >> 4;
  bf16x8 bfrag[4][4];
#pragma unroll
  for (int ct = 0; ct < 4; ++ct) {
    int col = ct * 16 + lrow;
#pragma unroll
    for (int ks = 0; ks < 4; ++ks)
      bfrag[ct][ks] = *(const bf16x8*)(w2T + (size_t)col * 128 + ks * 32 + lk * 8);
  }
  f32x4 acc[4] = {{0.f,0.f,0.f,0.f},{0.f,0.f,0.f,0.f},{0.f,0.f,0.f,0.f},{0.f,0.f,0.f,0.f}};
  int arow = wv * 16 + lrow;
#pragma unroll
  for (int ks = 0; ks < 4; ++ks) {
    int kb = (ks * 64 + lk * 16) ^ ((arow & 7) << 4);
    bf16x8 afrag = *(const bf16x8*)(aLds + arow * 256 + kb);
#pragma unroll
    for (int ct = 0; ct < 4; ++ct)
      acc[ct] = __builtin_amdgcn_mfma_f32_16x16x32_bf16(afrag, bfrag[ct][ks], acc[ct], 0, 0, 0);
  }
#pragma unroll
  for (int ct = 0; ct < 4; ++ct) {
    int col = ct * 16 + lrow;
#pragma unroll
    for (int j = 0; j < 4; ++j) {
      int row = nb + wv * 16 + lk * 4 + j;
      if (row < N_NODES) hs2[(size_t)row * 64 + col] = f2bf(acc[ct][j]);
    }
  }
}

// as[n] = hs[n].asrc ; ad[n] = xin[n].cdst   (one wave per node)
template <int C, bool XBF>
__global__ __launch_bounds__(256) void k_alpha(
    const unsigned short* __restrict__ hs, const float* __restrict__ asrc,
    const void* __restrict__ xin, const float* __restrict__ cdst,
    float* __restrict__ as_, float* __restrict__ ad_) {
  int node = (int)((blockIdx.x * 256 + threadIdx.x) >> 6);
  if (node >= N_NODES) return;
  int lane = threadIdx.x & 63;
  float sa = 0.f;
#pragma unroll
  for (int k = lane; k < C; k += 64) sa += bf2f(hs[(size_t)node * C + k]) * asrc[k];
  float sd = 0.f;
  if (XBF) {
    const unsigned short* xb = (const unsigned short*)xin;
#pragma unroll
    for (int k = lane; k < 128; k += 64) sd += bf2f(xb[(size_t)node * 128 + k]) * cdst[k];
  } else {
    const float* xf = (const float*)xin;
#pragma unroll
    for (int k = lane; k < 128; k += 64) sd += xf[(size_t)node * 128 + k] * cdst[k];
  }
#pragma unroll
  for (int o = 32; o > 0; o >>= 1) {
    sa += __shfl_xor(sa, o, 64);
    sd += __shfl_xor(sd, o, 64);
  }
  if (lane == 0) { as_[node] = sa; ad_[node] = sd; }
}

// XCD-partitioned: block b counts only dst in [(b&7)*6250, +6250)
__global__ void k_count(const int* __restrict__ ei, const int* __restrict__ flag,
                        int* __restrict__ deg) {
  int part = blockIdx.x & (NPART - 1);
  int e = (blockIdx.x >> 3) * 256 + threadIdx.x;
  if (e < N_EDGES) {
    int f = *flag;
    int d = clampN(ei[(size_t)(N_EDGES + e) << f]);
    int lo = part * PART_SZ;
    if (d >= lo && d < lo + PART_SZ) atomicAdd(&deg[d], 1);
  }
}

__global__ __launch_bounds__(256) void k_scan1(const int* __restrict__ deg,
                                               int* __restrict__ offs,
                                               int* __restrict__ bsums, int n) {
  __shared__ int wsum[4];
  int i = blockIdx.x * 256 + threadIdx.x;
  int lane = threadIdx.x & 63, wid = threadIdx.x >> 6;
  int v = (i < n) ? deg[i] : 0;
  int s = v;
#pragma unroll
  for (int o = 1; o < 64; o <<= 1) { int t = __shfl_up(s, o, 64); if (lane >= o) s += t; }
  if (lane == 63) wsum[wid] = s;
  __syncthreads();
  if (threadIdx.x == 0) {
    int a = 0;
#pragma unroll
    for (int w = 0; w < 4; ++w) { a += wsum[w]; wsum[w] = a; }
  }
  __syncthreads();
  int base = (wid > 0) ? wsum[wid - 1] : 0;
  if (i < n) offs[i] = base + s - v;
  if (threadIdx.x == 0) bsums[blockIdx.x] = wsum[3];
}

__global__ __launch_bounds__(256) void k_scan2(int* __restrict__ bsums, int nb,
                                               int* __restrict__ offs, int n, int etot) {
  __shared__ int wsum[4];
  int tid = threadIdx.x, lane = tid & 63, wid = tid >> 6;
  int v = (tid < nb) ? bsums[tid] : 0;
  int s = v;
#pragma unroll
  for (int o = 1; o < 64; o <<= 1) { int t = __shfl_up(s, o, 64); if (lane >= o) s += t; }
  if (lane == 63) wsum[wid] = s;
  __syncthreads();
  if (tid == 0) {
    int a = 0;
#pragma unroll
    for (int w = 0; w < 4; ++w) { a += wsum[w]; wsum[w] = a; }
  }
  __syncthreads();
  int base = (wid > 0) ? wsum[wid - 1] : 0;
  if (tid < nb) bsums[tid] = base + s - v;
  if (tid == 0) offs[n] = etot;
}

__global__ __launch_bounds__(256) void k_scan3(int* __restrict__ offs, int* __restrict__ cursor,
                                               const int* __restrict__ bsums, int n) {
  int i = blockIdx.x * 256 + threadIdx.x;
  if (i < n) {
    int o = offs[i] + bsums[blockIdx.x];
    offs[i] = o;
    cursor[i] = o;
  }
}

// XCD-partitioned CSR fill: only ssrc (4B/edge); writers of a line stay on one XCD-group
__global__ void k_fill(const int* __restrict__ ei, const int* __restrict__ flag,
                       int* __restrict__ cursor, int* __restrict__ ssrc) {
  int part = blockIdx.x & (NPART - 1);
  int e = (blockIdx.x >> 3) * 256 + threadIdx.x;
  if (e < N_EDGES) {
    int f = *flag;
    int d = clampN(ei[(size_t)(N_EDGES + e) << f]);
    int lo = part * PART_SZ;
    if (d >= lo && d < lo + PART_SZ) {
      int s = clampN(ei[(size_t)e << f]);
      int p = atomicAdd(&cursor[d], 1);
      if ((unsigned)p < (unsigned)N_EDGES) ssrc[p] = s;
    }
  }
}

// layer-1 agg: inline score (no-max softmax), 4 edge-slots x 16 lanes, fused relu(+b1+lin)
__global__ __launch_bounds__(256) void k_agg1(
    const int* __restrict__ offs, const int* __restrict__ ssrc,
    const float* __restrict__ as_, const float* __restrict__ ad_,
    const unsigned short* __restrict__ hs1, const float* __restrict__ b1,
    unsigned short* __restrict__ linzb) {
  int node = (int)((blockIdx.x * 256 + threadIdx.x) >> 6);
  if (node >= N_NODES) return;
  int lane = threadIdx.x & 63;
  int g = lane >> 4, cl = lane & 15;
  int o0 = offs[node], o1 = offs[node + 1];
  if (!((unsigned)o0 <= (unsigned)N_EDGES && (unsigned)o1 <= (unsigned)N_EDGES && o0 <= o1))
    { o0 = 0; o1 = 0; }
  int deg = o1 - o0;
  float ad = ad_[node];
  float acc[8];
#pragma unroll
  for (int k = 0; k < 8; ++k) acc[k] = 0.f;
  float ssum = 0.f;
  for (int j = g; j < deg; j += 4) {
    int s = clampN(ssrc[o0 + j]);
    float e = as_[s] + ad;
    e = e > 0.f ? e : 0.2f * e;
    float w = __expf(e);
    uint4 hv = *(const uint4*)(hs1 + (size_t)s * 128 + cl * 8);
    ssum += w;
    acc[0] += w * __uint_as_float(hv.x << 16);
    acc[1] += w * __uint_as_float(hv.x & 0xffff0000u);
    acc[2] += w * __uint_as_float(hv.y << 16);
    acc[3] += w * __uint_as_float(hv.y & 0xffff0000u);
    acc[4] += w * __uint_as_float(hv.z << 16);
    acc[5] += w * __uint_as_float(hv.z & 0xffff0000u);
    acc[6] += w * __uint_as_float(hv.w << 16);
    acc[7] += w * __uint_as_float(hv.w & 0xffff0000u);
  }
  ssum += __shfl_xor(ssum, 16, 64);
  ssum += __shfl_xor(ssum, 32, 64);
#pragma unroll
  for (int k = 0; k < 8; ++k) {
    acc[k] += __shfl_xor(acc[k], 16, 64);
    acc[k] += __shfl_xor(acc[k], 32, 64);
  }
  if (g == 0) {
    float inv = 1.f / (ssum + 1e-16f);
    uint4 lv = *(const uint4*)(linzb + (size_t)node * 128 + cl * 8);
    float4 ba = *(const float4*)(b1 + cl * 8);
    float4 bb = *(const float4*)(b1 + cl * 8 + 4);
    float z[8];
    z[0] = acc[0] * inv + ba.x + __uint_as_float(lv.x << 16);
    z[1] = acc[1] * inv + ba.y + __uint_as_float(lv.x & 0xffff0000u);
    z[2] = acc[2] * inv + ba.z + __uint_as_float(lv.y << 16);
    z[3] = acc[3] * inv + ba.w + __uint_as_float(lv.y & 0xffff0000u);
    z[4] = acc[4] * inv + bb.x + __uint_as_float(lv.z << 16);
    z[5] = acc[5] * inv + bb.y + __uint_as_float(lv.z & 0xffff0000u);
    z[6] = acc[6] * inv + bb.z + __uint_as_float(lv.w << 16);
    z[7] = acc[7] * inv + bb.w + __uint_as_float(lv.w & 0xffff0000u);
#pragma unroll
    for (int k = 0; k < 8; ++k) z[k] = z[k] > 0.f ? z[k] : 0.f;
    uint4 ov;
    ov.x = (unsigned)f2bf(z[0]) | ((unsigned)f2bf(z[1]) << 16);
    ov.y = (unsigned)f2bf(z[2]) | ((unsigned)f2bf(z[3]) << 16);
    ov.z = (unsigned)f2bf(z[4]) | ((unsigned)f2bf(z[5]) << 16);
    ov.w = (unsigned)f2bf(z[6]) | ((unsigned)f2bf(z[7]) << 16);
    *(uint4*)(linzb + (size_t)node * 128 + cl * 8) = ov;
  }
}

// layer-2 agg: inline score, 8 edge-slots x 8 lanes; fp32 out (+b2)
__global__ __launch_bounds__(256) void k_agg2(
    const int* __restrict__ offs, const int* __restrict__ ssrc,
    const float* __restrict__ as_, const float* __restrict__ ad_,
    const unsigned short* __restrict__ hs2, const float* __restrict__ b2,
    float* __restrict__ out) {
  int node = (int)((blockIdx.x * 256 + threadIdx.x) >> 6);
  if (node >= N_NODES) return;
  int lane = threadIdx.x & 63;
  int g = lane >> 3, cl = lane & 7;
  int o0 = offs[node], o1 = offs[node + 1];
  if (!((unsigned)o0 <= (unsigned)N_EDGES && (unsigned)o1 <= (unsigned)N_EDGES && o0 <= o1))
    { o0 = 0; o1 = 0; }
  int deg = o1 - o0;
  float ad = ad_[node];
  float acc[8];
#pragma unroll
  for (int k = 0; k < 8; ++k) acc[k] = 0.f;
  float ssum = 0.f;
  for (int j = g; j < deg; j += 8) {
    int s = clampN(ssrc[o0 + j]);
    float e = as_[s] + ad;
    e = e > 0.f ? e : 0.2f * e;
    float w = __expf(e);
    uint4 hv = *(const uint4*)(hs2 + (size_t)s * 64 + cl * 8);
    ssum += w;
    acc[0] += w * __uint_as_float(hv.x << 16);
    acc[1] += w * __uint_as_float(hv.x & 0xffff0000u);
    acc[2] += w * __uint_as_float(hv.y << 16);
    acc[3] += w * __uint_as_float(hv.y & 0xffff0000u);
    acc[4] += w * __uint_as_float(hv.z << 16);
    acc[5] += w * __uint_as_float(hv.z & 0xffff0000u);
    acc[6] += w * __uint_as_float(hv.w << 16);
    acc[7] += w * __uint_as_float(hv.w & 0xffff0000u);
  }
  ssum += __shfl_xor(ssum, 8, 64);
  ssum += __shfl_xor(ssum, 16, 64);
  ssum += __shfl_xor(ssum, 32, 64);
#pragma unroll
  for (int k = 0; k < 8; ++k) {
    acc[k] += __shfl_xor(acc[k], 8, 64);
    acc[k] += __shfl_xor(acc[k], 16, 64);
    acc[k] += __shfl_xor(acc[k], 32, 64);
  }
  if (g == 0) {
    float inv = 1.f / (ssum + 1e-16f);
    float4 ba = *(const float4*)(b2 + cl * 8);
    float4 bb = *(const float4*)(b2 + cl * 8 + 4);
    float4 oa, ob;
    oa.x = acc[0] * inv + ba.x;
    oa.y = acc[1] * inv + ba.y;
    oa.z = acc[2] * inv + ba.z;
    oa.w = acc[3] * inv + ba.w;
    ob.x = acc[4] * inv + bb.x;
    ob.y = acc[5] * inv + bb.y;
    ob.z = acc[6] * inv + bb.z;
    ob.w = acc[7] * inv + bb.w;
    *(float4*)(out + (size_t)node * 64 + cl * 8) = oa;
    *(float4*)(out + (size_t)node * 64 + cl * 8 + 4) = ob;
  }
}

extern "C" void kernel_launch(void* const* d_in, const int* in_sizes, int n_in,
                              void* d_out, int out_size, void* d_ws, size_t ws_size,
                              hipStream_t stream) {
  (void)in_sizes; (void)n_in;
  const float* x      = (const float*)d_in[0];
  const int*   ei     = (const int*)d_in[1];
  const float* lin1_w = (const float*)d_in[2];
  const float* lin1_b = (const float*)d_in[3];
  const float* w1_src = (const float*)d_in[4];
  const float* w1_dst = (const float*)d_in[5];
  const float* a1_src = (const float*)d_in[6];
  const float* a1_dst = (const float*)d_in[7];
  const float* b1     = (const float*)d_in[8];
  const float* w2_src = (const float*)d_in[9];
  const float* w2_dst = (const float*)d_in[10];
  const float* a2_src = (const float*)d_in[11];
  const float* a2_dst = (const float*)d_in[12];
  const float* b2     = (const float*)d_in[13];
  float* out = (float*)d_out;

  char* ws = (char*)d_ws;
  size_t off = 0;
  auto alloc = [&](size_t bytes) -> void* {
    void* p = ws + off;
    off += (bytes + 255) & ~(size_t)255;
    return p;
  };
  int* flag    = (int*)alloc(256);
  float* c1dst = (float*)alloc(128 * 4);
  float* c2dst = (float*)alloc(128 * 4);
  unsigned short* w1T = (unsigned short*)alloc(256 * 128 * 2);
  unsigned short* w2T = (unsigned short*)alloc(64 * 128 * 2);
  int* deg     = (int*)alloc((size_t)N_NODES * 4);
  int* offs    = (int*)alloc((size_t)(N_NODES + 1) * 4);
  int* cursor  = (int*)alloc((size_t)N_NODES * 4);
  int* bsums   = (int*)alloc(1024);
  float* as1   = (float*)alloc((size_t)N_NODES * 4);
  float* ad1   = (float*)alloc((size_t)N_NODES * 4);
  float* as2   = (float*)alloc((size_t)N_NODES * 4);
  float* ad2   = (float*)alloc((size_t)N_NODES * 4);
  int* ssrc    = (int*)alloc((size_t)N_EDGES * 4);
  unsigned short* hs1   = (unsigned short*)alloc((size_t)N_NODES * 128 * 2);
  unsigned short* hs2   = (unsigned short*)alloc((size_t)N_NODES * 64 * 2);
  unsigned short* linzb = (unsigned short*)alloc((size_t)N_NODES * 128 * 2);

  if (off > ws_size) {
    k_zero_out<<<(out_size + 255) / 256, 256, 0, stream>>>(out, out_size);
    return;
  }

  int ebl8 = NPART * ((N_EDGES + 255) / 256);  // 25000
  int nbl = (N_NODES + 3) / 4;                 // 12500
  hipMemsetAsync(deg, 0, (size_t)N_NODES * 4, stream);
  k_detect<<<1, 64, 0, stream>>>(ei, flag);
  k_prepw<<<161, 256, 0, stream>>>(w1_src, lin1_w, w2_src, w1_dst, a1_dst, w2_dst, a2_dst,
                                   w1T, w2T, c1dst, c2dst);
  k_gemm1<<<N_NODES / 16, 256, 0, stream>>>(x, w1T, lin1_b, hs1, linzb);
  k_alpha<128, false><<<nbl, 256, 0, stream>>>(hs1, a1_src, x, c1dst, as1, ad1);
  k_count<<<ebl8, 256, 0, stream>>>(ei, flag, deg);
  int nb = (N_NODES + 255) / 256;              // 196
  k_scan1<<<nb, 256, 0, stream>>>(deg, offs, bsums, N_NODES);
  k_scan2<<<1, 256, 0, stream>>>(bsums, nb, offs, N_NODES, N_EDGES);
  k_scan3<<<nb, 256, 0, stream>>>(offs, cursor, bsums, N_NODES);
  k_fill<<<ebl8, 256, 0, stream>>>(ei, flag, cursor, ssrc);
  k_agg1<<<nbl, 256, 0, stream>>>(offs, ssrc, as1, ad1, hs1, b1, linzb);
  k_gemm2<<<(N_NODES + 63) / 64, 256, 0, stream>>>(linzb, w2T, hs2);
  k_alpha<64, true><<<nbl, 256, 0, stream>>>(hs2, a2_src, linzb, c2dst, as2, ad2);
  k_agg2<<<nbl, 256, 0, stream>>>(offs, ssrc, as2, ad2, hs2, b2, out);
}

// Round 7
// 222.728 us; speedup vs baseline: 1.7780x; 1.0016x over previous
//
#include <hip/hip_runtime.h>

static constexpr int N_NODES = 50000;
static constexpr int N_EDGES = 800000;
static constexpr int NPART = 8;               // XCD count
static constexpr int PART_SZ = N_NODES / NPART;  // 6250

typedef __attribute__((ext_vector_type(8))) short bf16x8;
typedef __attribute__((ext_vector_type(4))) float f32x4;

__device__ __forceinline__ float bf2f(unsigned short u) {
  union { unsigned int i; float f; } v; v.i = ((unsigned int)u) << 16; return v.f;
}
__device__ __forceinline__ unsigned short f2bf(float f) {
  union { unsigned int i; float f; } v; v.f = f;
  unsigned int r = (v.i + 0x7fffu + ((v.i >> 16) & 1u)) >> 16;
  return (unsigned short)r;
}
__device__ __forceinline__ int clampN(int v) {
  unsigned u = (unsigned)v; return (u < (unsigned)N_NODES) ? (int)u : 0;
}

__global__ void k_detect(const int* __restrict__ ei, int* __restrict__ flag) {
  if (threadIdx.x == 0 && blockIdx.x == 0) {
    int z = ei[1] | ei[3] | ei[5] | ei[7];
    *flag = (z == 0) ? 1 : 0;
  }
}

__global__ void k_zero_out(float* __restrict__ out, int n) {
  int i = blockIdx.x * 256 + threadIdx.x;
  if (i < n) out[i] = 0.f;
}

// edge_index -> compact int32 src/dst (handles int64 or int32 storage)
__global__ void k_compact(const int* __restrict__ ei, const int* __restrict__ flag,
                          int* __restrict__ s32, int* __restrict__ d32) {
  int e = blockIdx.x * 256 + threadIdx.x;
  if (e < N_EDGES) {
    int f = *flag;
    s32[e] = clampN(ei[(size_t)e << f]);
    d32[e] = clampN(ei[(size_t)(N_EDGES + e) << f]);
  }
}

// weights -> bf16 [col][k]; block 160 also computes c_dst vectors
__global__ void k_prepw(const float* __restrict__ w1_src, const float* __restrict__ wlin,
                        const float* __restrict__ w2_src,
                        const float* __restrict__ w1_dst, const float* __restrict__ a1_dst,
                        const float* __restrict__ w2_dst, const float* __restrict__ a2_dst,
                        unsigned short* __restrict__ w1T, unsigned short* __restrict__ w2T,
                        float* __restrict__ c1dst, float* __restrict__ c2dst) {
  int idx = blockIdx.x * 256 + threadIdx.x;
  if (idx < 256 * 128) {
    int c = idx >> 7, k = idx & 127;
    float v = (c < 128) ? w1_src[k * 128 + c] : wlin[k * 128 + (c - 128)];
    w1T[idx] = f2bf(v);
  } else if (idx < 256 * 128 + 64 * 128) {
    int r = idx - 256 * 128;
    int c = r >> 7, k = r & 127;
    w2T[r] = f2bf(w2_src[k * 64 + c]);
  } else if (blockIdx.x == 160) {
    int k = threadIdx.x;
    if (k < 128) {
      float s1 = 0.f;
      for (int c = 0; c < 128; ++c) s1 += w1_dst[k * 128 + c] * a1_dst[c];
      c1dst[k] = s1;
      float s2 = 0.f;
      for (int c = 0; c < 64; ++c) s2 += w2_dst[k * 64 + c] * a2_dst[c];
      c2dst[k] = s2;
    }
  }
}

// MFMA GEMM1 (64 rows/block): x @ {w1_src|lin1_w} -> hs1, linzb(+b); fused as1/ad1
__global__ __launch_bounds__(256) void k_gemm1(
    const float* __restrict__ x, const unsigned short* __restrict__ w1T,
    const float* __restrict__ lin_b, const float* __restrict__ a1_src,
    const float* __restrict__ c1dst,
    unsigned short* __restrict__ hs1, unsigned short* __restrict__ linzb,
    float* __restrict__ as1, float* __restrict__ ad1) {
  __shared__ unsigned char aLds[64 * 256];  // [64][128] bf16, XOR-swizzled
  int nb = blockIdx.x * 64;
  int tid = threadIdx.x;
#pragma unroll
  for (int i = 0; i < 4; ++i) {
    int t = tid + i * 256;
    int row = t >> 4, q = t & 15;           // q: 16B unit (8 bf16 = 8 fp32 in)
    int grow = nb + row; if (grow >= N_NODES) grow = N_NODES - 1;
    float4 va = *(const float4*)(x + (size_t)grow * 128 + q * 8);
    float4 vb = *(const float4*)(x + (size_t)grow * 128 + q * 8 + 4);
    uint4 o;
    o.x = (unsigned)f2bf(va.x) | ((unsigned)f2bf(va.y) << 16);
    o.y = (unsigned)f2bf(va.z) | ((unsigned)f2bf(va.w) << 16);
    o.z = (unsigned)f2bf(vb.x) | ((unsigned)f2bf(vb.y) << 16);
    o.w = (unsigned)f2bf(vb.z) | ((unsigned)f2bf(vb.w) << 16);
    int kb = (q * 16) ^ ((row & 7) << 4);
    *(uint4*)(aLds + row * 256 + kb) = o;
  }
  __syncthreads();
  int wv = tid >> 6, l = tid & 63;
  int lrow = l & 15, lk = l >> 4;
  // A fragments: rows wv*16..+15 (local), loaded once
  bf16x8 afrag[4];
#pragma unroll
  for (int ks = 0; ks < 4; ++ks) {
    int kb = (ks * 64 + lk * 16) ^ ((lrow & 7) << 4);
    afrag[ks] = *(const bf16x8*)(aLds + (wv * 16 + lrow) * 256 + kb);
  }
  float pa[4] = {0.f, 0.f, 0.f, 0.f};       // as1 partials (hs cols only)
#pragma unroll
  for (int ch = 0; ch < 4; ++ch) {          // 4 col-chunks of 64
    bf16x8 bfrag[4][4];
#pragma unroll
    for (int ct = 0; ct < 4; ++ct) {
      int col = ch * 64 + ct * 16 + lrow;
#pragma unroll
      for (int ks = 0; ks < 4; ++ks)
        bfrag[ct][ks] = *(const bf16x8*)(w1T + (size_t)col * 128 + ks * 32 + lk * 8);
    }
    f32x4 acc[4] = {{0.f,0.f,0.f,0.f},{0.f,0.f,0.f,0.f},{0.f,0.f,0.f,0.f},{0.f,0.f,0.f,0.f}};
#pragma unroll
    for (int ks = 0; ks < 4; ++ks)
#pragma unroll
      for (int ct = 0; ct < 4; ++ct)
        acc[ct] = __builtin_amdgcn_mfma_f32_16x16x32_bf16(afrag[ks], bfrag[ct][ks], acc[ct], 0, 0, 0);
#pragma unroll
    for (int ct = 0; ct < 4; ++ct) {
      int col = ch * 64 + ct * 16 + lrow;
      float av = (col < 128) ? a1_src[col] : 0.f;
#pragma unroll
      for (int j = 0; j < 4; ++j) {
        int row = nb + wv * 16 + lk * 4 + j;
        float v = acc[ct][j];
        if (row < N_NODES) {
          if (col < 128) hs1[(size_t)row * 128 + col] = f2bf(v);
          else linzb[(size_t)row * 128 + (col - 128)] = f2bf(v + lin_b[col - 128]);
        }
        if (col < 128) pa[j] += v * av;
      }
    }
  }
  // as1: reduce pa over the 16 lrow lanes
#pragma unroll
  for (int j = 0; j < 4; ++j) {
    pa[j] += __shfl_xor(pa[j], 1, 64);
    pa[j] += __shfl_xor(pa[j], 2, 64);
    pa[j] += __shfl_xor(pa[j], 4, 64);
    pa[j] += __shfl_xor(pa[j], 8, 64);
  }
  if (lrow == 0) {
#pragma unroll
    for (int j = 0; j < 4; ++j) {
      int row = nb + wv * 16 + lk * 4 + j;
      if (row < N_NODES) as1[row] = pa[j];
    }
  }
  // ad1 = x(bf16, LDS) . c1dst : lane -> row l>>2, k-quarter l&3
  {
    int r = wv * 16 + (l >> 2), kq = l & 3;
    float sd = 0.f;
#pragma unroll
    for (int b = 0; b < 4; ++b) {
      int kb = (kq * 64 + b * 16) ^ ((r & 7) << 4);
      bf16x8 v = *(const bf16x8*)(aLds + r * 256 + kb);
      int k0 = kq * 32 + b * 8;
      float4 ca = *(const float4*)(c1dst + k0);
      float4 cb = *(const float4*)(c1dst + k0 + 4);
      sd += bf2f((unsigned short)v[0]) * ca.x + bf2f((unsigned short)v[1]) * ca.y +
            bf2f((unsigned short)v[2]) * ca.z + bf2f((unsigned short)v[3]) * ca.w +
            bf2f((unsigned short)v[4]) * cb.x + bf2f((unsigned short)v[5]) * cb.y +
            bf2f((unsigned short)v[6]) * cb.z + bf2f((unsigned short)v[7]) * cb.w;
    }
    sd += __shfl_xor(sd, 1, 64);
    sd += __shfl_xor(sd, 2, 64);
    int row = nb + r;
    if (kq == 0 && row < N_NODES) ad1[row] = sd;
  }
}

// MFMA GEMM2 (64 rows/block): zb(bf16) @ w2_src -> hs2; fused as2/ad2
__global__ __launch_bounds__(256) void k_gemm2(
    const unsigned short* __restrict__ zb, const unsigned short* __restrict__ w2T,
    const float* __restrict__ a2_src, const float* __restrict__ c2dst,
    unsigned short* __restrict__ hs2, float* __restrict__ as2, float* __restrict__ ad2) {
  __shared__ unsigned char aLds[64 * 256];
  int nb = blockIdx.x * 64;
  int tid = threadIdx.x;
#pragma unroll
  for (int i = 0; i < 4; ++i) {
    int t = tid + i * 256;
    int row = t >> 4, q = t & 15;
    int grow = nb + row; if (grow >= N_NODES) grow = N_NODES - 1;
    uint4 v = *(const uint4*)(zb + (size_t)grow * 128 + q * 8);
    int kb = (q * 16) ^ ((row & 7) << 4);
    *(uint4*)(aLds + row * 256 + kb) = v;
  }
  __syncthreads();
  int wv = tid >> 6, l = tid & 63;
  int lrow = l & 15, lk = l >> 4;
  bf16x8 bfrag[4][4];
#pragma unroll
  for (int ct = 0; ct < 4; ++ct) {
    int col = ct * 16 + lrow;
#pragma unroll
    for (int ks = 0; ks < 4; ++ks)
      bfrag[ct][ks] = *(const bf16x8*)(w2T + (size_t)col * 128 + ks * 32 + lk * 8);
  }
  f32x4 acc[4] = {{0.f,0.f,0.f,0.f},{0.f,0.f,0.f,0.f},{0.f,0.f,0.f,0.f},{0.f,0.f,0.f,0.f}};
#pragma unroll
  for (int ks = 0; ks < 4; ++ks) {
    int kb = (ks * 64 + lk * 16) ^ ((lrow & 7) << 4);
    bf16x8 afrag = *(const bf16x8*)(aLds + (wv * 16 + lrow) * 256 + kb);
#pragma unroll
    for (int ct = 0; ct < 4; ++ct)
      acc[ct] = __builtin_amdgcn_mfma_f32_16x16x32_bf16(afrag, bfrag[ct][ks], acc[ct], 0, 0, 0);
  }
  float pa[4] = {0.f, 0.f, 0.f, 0.f};
#pragma unroll
  for (int ct = 0; ct < 4; ++ct) {
    int col = ct * 16 + lrow;
    float av = a2_src[col];
#pragma unroll
    for (int j = 0; j < 4; ++j) {
      int row = nb + wv * 16 + lk * 4 + j;
      if (row < N_NODES) hs2[(size_t)row * 64 + col] = f2bf(acc[ct][j]);
      pa[j] += acc[ct][j] * av;
    }
  }
#pragma unroll
  for (int j = 0; j < 4; ++j) {
    pa[j] += __shfl_xor(pa[j], 1, 64);
    pa[j] += __shfl_xor(pa[j], 2, 64);
    pa[j] += __shfl_xor(pa[j], 4, 64);
    pa[j] += __shfl_xor(pa[j], 8, 64);
  }
  if (lrow == 0) {
#pragma unroll
    for (int j = 0; j < 4; ++j) {
      int row = nb + wv * 16 + lk * 4 + j;
      if (row < N_NODES) as2[row] = pa[j];
    }
  }
  {
    int r = wv * 16 + (l >> 2), kq = l & 3;
    float sd = 0.f;
#pragma unroll
    for (int b = 0; b < 4; ++b) {
      int kb = (kq * 64 + b * 16) ^ ((r & 7) << 4);
      bf16x8 v = *(const bf16x8*)(aLds + r * 256 + kb);
      int k0 = kq * 32 + b * 8;
      float4 ca = *(const float4*)(c2dst + k0);
      float4 cb = *(const float4*)(c2dst + k0 + 4);
      sd += bf2f((unsigned short)v[0]) * ca.x + bf2f((unsigned short)v[1]) * ca.y +
            bf2f((unsigned short)v[2]) * ca.z + bf2f((unsigned short)v[3]) * ca.w +
            bf2f((unsigned short)v[4]) * cb.x + bf2f((unsigned short)v[5]) * cb.y +
            bf2f((unsigned short)v[6]) * cb.z + bf2f((unsigned short)v[7]) * cb.w;
    }
    sd += __shfl_xor(sd, 1, 64);
    sd += __shfl_xor(sd, 2, 64);
    int row = nb + r;
    if (kq == 0 && row < N_NODES) ad2[row] = sd;
  }
}

// XCD-partitioned count on compacted dst
__global__ void k_count(const int* __restrict__ d32, int* __restrict__ deg) {
  int part = blockIdx.x & (NPART - 1);
  int e = (blockIdx.x >> 3) * 256 + threadIdx.x;
  if (e < N_EDGES) {
    int d = d32[e];
    int lo = part * PART_SZ;
    if (d >= lo && d < lo + PART_SZ) atomicAdd(&deg[d], 1);
  }
}

__global__ __launch_bounds__(256) void k_scan1(const int* __restrict__ deg,
                                               int* __restrict__ offs,
                                               int* __restrict__ bsums, int n) {
  __shared__ int wsum[4];
  int i = blockIdx.x * 256 + threadIdx.x;
  int lane = threadIdx.x & 63, wid = threadIdx.x >> 6;
  int v = (i < n) ? deg[i] : 0;
  int s = v;
#pragma unroll
  for (int o = 1; o < 64; o <<= 1) { int t = __shfl_up(s, o, 64); if (lane >= o) s += t; }
  if (lane == 63) wsum[wid] = s;
  __syncthreads();
  if (threadIdx.x == 0) {
    int a = 0;
#pragma unroll
    for (int w = 0; w < 4; ++w) { a += wsum[w]; wsum[w] = a; }
  }
  __syncthreads();
  int base = (wid > 0) ? wsum[wid - 1] : 0;
  if (i < n) offs[i] = base + s - v;
  if (threadIdx.x == 0) bsums[blockIdx.x] = wsum[3];
}

__global__ __launch_bounds__(256) void k_scan2(int* __restrict__ bsums, int nb,
                                               int* __restrict__ offs, int n, int etot) {
  __shared__ int wsum[4];
  int tid = threadIdx.x, lane = tid & 63, wid = tid >> 6;
  int v = (tid < nb) ? bsums[tid] : 0;
  int s = v;
#pragma unroll
  for (int o = 1; o < 64; o <<= 1) { int t = __shfl_up(s, o, 64); if (lane >= o) s += t; }
  if (lane == 63) wsum[wid] = s;
  __syncthreads();
  if (tid == 0) {
    int a = 0;
#pragma unroll
    for (int w = 0; w < 4; ++w) { a += wsum[w]; wsum[w] = a; }
  }
  __syncthreads();
  int base = (wid > 0) ? wsum[wid - 1] : 0;
  if (tid < nb) bsums[tid] = base + s - v;
  if (tid == 0) offs[n] = etot;
}

__global__ __launch_bounds__(256) void k_scan3(int* __restrict__ offs, int* __restrict__ cursor,
                                               const int* __restrict__ bsums, int n) {
  int i = blockIdx.x * 256 + threadIdx.x;
  if (i < n) {
    int o = offs[i] + bsums[blockIdx.x];
    offs[i] = o;
    cursor[i] = o;
  }
}

// XCD-partitioned CSR fill on compacted arrays
__global__ void k_fill(const int* __restrict__ s32, const int* __restrict__ d32,
                       int* __restrict__ cursor, int* __restrict__ ssrc) {
  int part = blockIdx.x & (NPART - 1);
  int e = (blockIdx.x >> 3) * 256 + threadIdx.x;
  if (e < N_EDGES) {
    int d = d32[e];
    int lo = part * PART_SZ;
    if (d >= lo && d < lo + PART_SZ) {
      int p = atomicAdd(&cursor[d], 1);
      if ((unsigned)p < (unsigned)N_EDGES) ssrc[p] = s32[e];
    }
  }
}

// layer-1 agg: inline score (no-max softmax), 4 edge-slots x 16 lanes, fused relu(+b1+lin)
__global__ __launch_bounds__(256) void k_agg1(
    const int* __restrict__ offs, const int* __restrict__ ssrc,
    const float* __restrict__ as_, const float* __restrict__ ad_,
    const unsigned short* __restrict__ hs1, const float* __restrict__ b1,
    unsigned short* __restrict__ linzb) {
  int node = (int)((blockIdx.x * 256 + threadIdx.x) >> 6);
  if (node >= N_NODES) return;
  int lane = threadIdx.x & 63;
  int g = lane >> 4, cl = lane & 15;
  int o0 = offs[node], o1 = offs[node + 1];
  if (!((unsigned)o0 <= (unsigned)N_EDGES && (unsigned)o1 <= (unsigned)N_EDGES && o0 <= o1))
    { o0 = 0; o1 = 0; }
  int deg = o1 - o0;
  float ad = ad_[node];
  float acc[8];
#pragma unroll
  for (int k = 0; k < 8; ++k) acc[k] = 0.f;
  float ssum = 0.f;
  for (int j = g; j < deg; j += 4) {
    int s = clampN(ssrc[o0 + j]);
    float e = as_[s] + ad;
    e = e > 0.f ? e : 0.2f * e;
    float w = __expf(e);
    uint4 hv = *(const uint4*)(hs1 + (size_t)s * 128 + cl * 8);
    ssum += w;
    acc[0] += w * __uint_as_float(hv.x << 16);
    acc[1] += w * __uint_as_float(hv.x & 0xffff0000u);
    acc[2] += w * __uint_as_float(hv.y << 16);
    acc[3] += w * __uint_as_float(hv.y & 0xffff0000u);
    acc[4] += w * __uint_as_float(hv.z << 16);
    acc[5] += w * __uint_as_float(hv.z & 0xffff0000u);
    acc[6] += w * __uint_as_float(hv.w << 16);
    acc[7] += w * __uint_as_float(hv.w & 0xffff0000u);
  }
  ssum += __shfl_xor(ssum, 16, 64);
  ssum += __shfl_xor(ssum, 32, 64);
#pragma unroll
  for (int k = 0; k < 8; ++k) {
    acc[k] += __shfl_xor(acc[k], 16, 64);
    acc[k] += __shfl_xor(acc[k], 32, 64);
  }
  if (g == 0) {
    float inv = 1.f / (ssum + 1e-16f);
    uint4 lv = *(const uint4*)(linzb + (size_t)node * 128 + cl * 8);
    float4 ba = *(const float4*)(b1 + cl * 8);
    float4 bb = *(const float4*)(b1 + cl * 8 + 4);
    float z[8];
    z[0] = acc[0] * inv + ba.x + __uint_as_float(lv.x << 16);
    z[1] = acc[1] * inv + ba.y + __uint_as_float(lv.x & 0xffff0000u);
    z[2] = acc[2] * inv + ba.z + __uint_as_float(lv.y << 16);
    z[3] = acc[3] * inv + ba.w + __uint_as_float(lv.y & 0xffff0000u);
    z[4] = acc[4] * inv + bb.x + __uint_as_float(lv.z << 16);
    z[5] = acc[5] * inv + bb.y + __uint_as_float(lv.z & 0xffff0000u);
    z[6] = acc[6] * inv + bb.z + __uint_as_float(lv.w << 16);
    z[7] = acc[7] * inv + bb.w + __uint_as_float(lv.w & 0xffff0000u);
#pragma unroll
    for (int k = 0; k < 8; ++k) z[k] = z[k] > 0.f ? z[k] : 0.f;
    uint4 ov;
    ov.x = (unsigned)f2bf(z[0]) | ((unsigned)f2bf(z[1]) << 16);
    ov.y = (unsigned)f2bf(z[2]) | ((unsigned)f2bf(z[3]) << 16);
    ov.z = (unsigned)f2bf(z[4]) | ((unsigned)f2bf(z[5]) << 16);
    ov.w = (unsigned)f2bf(z[6]) | ((unsigned)f2bf(z[7]) << 16);
    *(uint4*)(linzb + (size_t)node * 128 + cl * 8) = ov;
  }
}

// layer-2 agg: inline score, 8 edge-slots x 8 lanes; fp32 out (+b2)
__global__ __launch_bounds__(256) void k_agg2(
    const int* __restrict__ offs, const int* __restrict__ ssrc,
    const float* __restrict__ as_, const float* __restrict__ ad_,
    const unsigned short* __restrict__ hs2, const float* __restrict__ b2,
    float* __restrict__ out) {
  int node = (int)((blockIdx.x * 256 + threadIdx.x) >> 6);
  if (node >= N_NODES) return;
  int lane = threadIdx.x & 63;
  int g = lane >> 3, cl = lane & 7;
  int o0 = offs[node], o1 = offs[node + 1];
  if (!((unsigned)o0 <= (unsigned)N_EDGES && (unsigned)o1 <= (unsigned)N_EDGES && o0 <= o1))
    { o0 = 0; o1 = 0; }
  int deg = o1 - o0;
  float ad = ad_[node];
  float acc[8];
#pragma unroll
  for (int k = 0; k < 8; ++k) acc[k] = 0.f;
  float ssum = 0.f;
  for (int j = g; j < deg; j += 8) {
    int s = clampN(ssrc[o0 + j]);
    float e = as_[s] + ad;
    e = e > 0.f ? e : 0.2f * e;
    float w = __expf(e);
    uint4 hv = *(const uint4*)(hs2 + (size_t)s * 64 + cl * 8);
    ssum += w;
    acc[0] += w * __uint_as_float(hv.x << 16);
    acc[1] += w * __uint_as_float(hv.x & 0xffff0000u);
    acc[2] += w * __uint_as_float(hv.y << 16);
    acc[3] += w * __uint_as_float(hv.y & 0xffff0000u);
    acc[4] += w * __uint_as_float(hv.z << 16);
    acc[5] += w * __uint_as_float(hv.z & 0xffff0000u);
    acc[6] += w * __uint_as_float(hv.w << 16);
    acc[7] += w * __uint_as_float(hv.w & 0xffff0000u);
  }
  ssum += __shfl_xor(ssum, 8, 64);
  ssum += __shfl_xor(ssum, 16, 64);
  ssum += __shfl_xor(ssum, 32, 64);
#pragma unroll
  for (int k = 0; k < 8; ++k) {
    acc[k] += __shfl_xor(acc[k], 8, 64);
    acc[k] += __shfl_xor(acc[k], 16, 64);
    acc[k] += __shfl_xor(acc[k], 32, 64);
  }
  if (g == 0) {
    float inv = 1.f / (ssum + 1e-16f);
    float4 ba = *(const float4*)(b2 + cl * 8);
    float4 bb = *(const float4*)(b2 + cl * 8 + 4);
    float4 oa, ob;
    oa.x = acc[0] * inv + ba.x;
    oa.y = acc[1] * inv + ba.y;
    oa.z = acc[2] * inv + ba.z;
    oa.w = acc[3] * inv + ba.w;
    ob.x = acc[4] * inv + bb.x;
    ob.y = acc[5] * inv + bb.y;
    ob.z = acc[6] * inv + bb.z;
    ob.w = acc[7] * inv + bb.w;
    *(float4*)(out + (size_t)node * 64 + cl * 8) = oa;
    *(float4*)(out + (size_t)node * 64 + cl * 8 + 4) = ob;
  }
}

extern "C" void kernel_launch(void* const* d_in, const int* in_sizes, int n_in,
                              void* d_out, int out_size, void* d_ws, size_t ws_size,
                              hipStream_t stream) {
  (void)in_sizes; (void)n_in;
  const float* x      = (const float*)d_in[0];
  const int*   ei     = (const int*)d_in[1];
  const float* lin1_w = (const float*)d_in[2];
  const float* lin1_b = (const float*)d_in[3];
  const float* w1_src = (const float*)d_in[4];
  const float* w1_dst = (const float*)d_in[5];
  const float* a1_src = (const float*)d_in[6];
  const float* a1_dst = (const float*)d_in[7];
  const float* b1     = (const float*)d_in[8];
  const float* w2_src = (const float*)d_in[9];
  const float* w2_dst = (const float*)d_in[10];
  const float* a2_src = (const float*)d_in[11];
  const float* a2_dst = (const float*)d_in[12];
  const float* b2     = (const float*)d_in[13];
  float* out = (float*)d_out;

  char* ws = (char*)d_ws;
  size_t off = 0;
  auto alloc = [&](size_t bytes) -> void* {
    void* p = ws + off;
    off += (bytes + 255) & ~(size_t)255;
    return p;
  };
  int* flag    = (int*)alloc(256);
  float* c1dst = (float*)alloc(128 * 4);
  float* c2dst = (float*)alloc(128 * 4);
  unsigned short* w1T = (unsigned short*)alloc(256 * 128 * 2);
  unsigned short* w2T = (unsigned short*)alloc(64 * 128 * 2);
  int* deg     = (int*)alloc((size_t)N_NODES * 4);
  int* offs    = (int*)alloc((size_t)(N_NODES + 1) * 4);
  int* cursor  = (int*)alloc((size_t)N_NODES * 4);
  int* bsums   = (int*)alloc(1024);
  float* as1   = (float*)alloc((size_t)N_NODES * 4);
  float* ad1   = (float*)alloc((size_t)N_NODES * 4);
  float* as2   = (float*)alloc((size_t)N_NODES * 4);
  float* ad2   = (float*)alloc((size_t)N_NODES * 4);
  int* s32     = (int*)alloc((size_t)N_EDGES * 4);
  int* d32     = (int*)alloc((size_t)N_EDGES * 4);
  int* ssrc    = (int*)alloc((size_t)N_EDGES * 4);
  unsigned short* hs1   = (unsigned short*)alloc((size_t)N_NODES * 128 * 2);
  unsigned short* hs2   = (unsigned short*)alloc((size_t)N_NODES * 64 * 2);
  unsigned short* linzb = (unsigned short*)alloc((size_t)N_NODES * 128 * 2);

  if (off > ws_size) {
    k_zero_out<<<(out_size + 255) / 256, 256, 0, stream>>>(out, out_size);
    return;
  }

  int ebl  = (N_EDGES + 255) / 256;   // 3125
  int ebl8 = NPART * ebl;             // 25000
  int nbl  = (N_NODES + 3) / 4;       // 12500
  int gbl  = (N_NODES + 63) / 64;     // 782
  hipMemsetAsync(deg, 0, (size_t)N_NODES * 4, stream);
  k_detect<<<1, 64, 0, stream>>>(ei, flag);
  k_prepw<<<161, 256, 0, stream>>>(w1_src, lin1_w, w2_src, w1_dst, a1_dst, w2_dst, a2_dst,
                                   w1T, w2T, c1dst, c2dst);
  k_compact<<<ebl, 256, 0, stream>>>(ei, flag, s32, d32);
  k_gemm1<<<gbl, 256, 0, stream>>>(x, w1T, lin1_b, a1_src, c1dst, hs1, linzb, as1, ad1);
  k_count<<<ebl8, 256, 0, stream>>>(d32, deg);
  int nb = (N_NODES + 255) / 256;     // 196
  k_scan1<<<nb, 256, 0, stream>>>(deg, offs, bsums, N_NODES);
  k_scan2<<<1, 256, 0, stream>>>(bsums, nb, offs, N_NODES, N_EDGES);
  k_scan3<<<nb, 256, 0, stream>>>(offs, cursor, bsums, N_NODES);
  k_fill<<<ebl8, 256, 0, stream>>>(s32, d32, cursor, ssrc);
  k_agg1<<<nbl, 256, 0, stream>>>(offs, ssrc, as1, ad1, hs1, b1, linzb);
  k_gemm2<<<gbl, 256, 0, stream>>>(linzb, w2T, a2_src, c2dst, hs2, as2, ad2);
  k_agg2<<<nbl, 256, 0, stream>>>(offs, ssrc, as2, ad2, hs2, b2, out);
}